// Round 3
// baseline (451.403 us; speedup 1.0000x reference)
//
#include <hip/hip_runtime.h>

typedef __attribute__((ext_vector_type(8))) short short8;
typedef __attribute__((ext_vector_type(4))) float f32x4;

#define MFMA16(a, b, c) __builtin_amdgcn_mfma_f32_16x16x32_bf16((a), (b), (c), 0, 0, 0)

static __device__ __forceinline__ unsigned short f2bf(float f) {
    unsigned int u = __float_as_uint(f);
    return (unsigned short)((u + 0x7fffu + ((u >> 16) & 1u)) >> 16);
}

// async 16B/lane global->LDS; LDS dest = wave-uniform base + lane*16
static __device__ __forceinline__ void glds16(const unsigned short* g, unsigned short* l) {
    __builtin_amdgcn_global_load_lds(
        (const __attribute__((address_space(1))) unsigned int*)g,
        (__attribute__((address_space(3))) unsigned int*)l, 16, 0, 0);
}

// -------- merged weight convert+transpose: W[K,N] fp32 -> WT[N,K] bf16 ------
__global__ __launch_bounds__(256) void convt_all_kernel(
    const float* __restrict__ w_qkv, const float* __restrict__ w_proj,
    const float* __restrict__ w_fc1, const float* __restrict__ w_fc2,
    unsigned short* __restrict__ wqkvT, unsigned short* __restrict__ wprojT,
    unsigned short* __restrict__ wfc1T, unsigned short* __restrict__ wfc2T) {
    __shared__ unsigned short Ts[32][33];
    int id = blockIdx.x;
    const float* W; unsigned short* WT; int K, N, bx, by;
    if (id < 3072)      { W = w_qkv;  WT = wqkvT;  K = 1024; N = 3072; bx = id % 96;  by = id / 96; }
    else if (id < 4096) { id -= 3072; W = w_proj; WT = wprojT; K = 1024; N = 1024; bx = id & 31; by = id >> 5; }
    else if (id < 8192) { id -= 4096; W = w_fc1;  WT = wfc1T;  K = 1024; N = 4096; bx = id & 127; by = id >> 7; }
    else                { id -= 8192; W = w_fc2;  WT = wfc2T;  K = 4096; N = 1024; bx = id & 31; by = id >> 5; }
    int t = threadIdx.x;
    int bk = by * 32, bn = bx * 32;
    int r = t >> 3, c = (t & 7) * 4;
    float4 w = *(const float4*)&W[(size_t)(bk + r) * N + bn + c];
    Ts[c + 0][r] = f2bf(w.x); Ts[c + 1][r] = f2bf(w.y);
    Ts[c + 2][r] = f2bf(w.z); Ts[c + 3][r] = f2bf(w.w);
    __syncthreads();
    ushort4 o;
    o.x = Ts[r][c]; o.y = Ts[r][c + 1]; o.z = Ts[r][c + 2]; o.w = Ts[r][c + 3];
    *(ushort4*)&WT[(size_t)(bn + r) * K + bk + c] = o;
}

// ---------------- LayerNorm: fp32 in -> bf16 out ----------------------------
__global__ __launch_bounds__(256) void ln_kernel(const float* __restrict__ x,
                                                 const float* __restrict__ g,
                                                 const float* __restrict__ be,
                                                 unsigned short* __restrict__ y) {
    int row = blockIdx.x;
    const float* xr = x + (size_t)row * 1024;
    unsigned short* yr = y + (size_t)row * 1024;
    int t = threadIdx.x;
    float v[4];
    float sum = 0.f, sq = 0.f;
#pragma unroll
    for (int i = 0; i < 4; ++i) {
        float f = xr[t + i * 256];
        v[i] = f; sum += f; sq += f * f;
    }
#pragma unroll
    for (int o = 32; o > 0; o >>= 1) { sum += __shfl_down(sum, o); sq += __shfl_down(sq, o); }
    __shared__ float red[8];
    int wave = t >> 6, lane = t & 63;
    if (lane == 0) { red[wave] = sum; red[4 + wave] = sq; }
    __syncthreads();
    sum = red[0] + red[1] + red[2] + red[3];
    sq  = red[4] + red[5] + red[6] + red[7];
    float mean = sum * (1.f / 1024.f);
    float var  = sq * (1.f / 1024.f) - mean * mean;
    float rstd = rsqrtf(var + 1e-5f);
#pragma unroll
    for (int i = 0; i < 4; ++i) {
        int c = t + i * 256;
        yr[c] = f2bf((v[i] - mean) * rstd * g[c] + be[c]);
    }
}

// -------- GEMM 256x256: C = act(A @ BT^T + bias) + resid --------------------
// 512 threads = 8 waves (2 M x 4 N), each wave owns a 128x64 output tile
// (acc[8][4] f32x4). K-step 32, FOUR-buffer LDS ring (4 x 32KB = 128KB),
// counted-vmcnt pipeline depth 3 (NL=4 glds16/wave/step -> 12/8/4/0 ladder).
// Halves global->LDS bytes per FLOP vs the 128^2 tile: (256+256)/(256*256)
// vs (128+128)/(128*128). One block/CU (VGPR ~200 -> 2 waves/SIMD).
// Both-sides XOR swizzle (verified R1: bank conflicts -> 0): glds16 dest
// linear, per-lane GLOBAL source column pre-swizzled by ((srow>>1)&3),
// ds_read applies quad ^ ((lm>>1)&3).
// Requires M%256==0, N%256==0, gridDim.y%8==0, K%32==0, K>=128.
__global__ __launch_bounds__(512) void gemm256_kernel(const unsigned short* __restrict__ A,
                                                      const unsigned short* __restrict__ BT,
                                                      const float* __restrict__ bias,
                                                      const float* __restrict__ resid,
                                                      void* __restrict__ C,
                                                      int M, int N, int K, int act, int cF32) {
    __shared__ __align__(16) unsigned short As[4][256][32];
    __shared__ __align__(16) unsigned short Bs[4][256][32];
    int t = threadIdx.x, wave = t >> 6, lane = t & 63;
    int lm = lane & 15, quad = lane >> 4;
    int wm = (wave >> 2) * 128, wn = (wave & 3) * 64;

    int id = blockIdx.y * gridDim.x + blockIdx.x;
    int gsz = gridDim.x * 8;
    int grp = id / gsz, rem = id % gsz;
    int br = (grp * 8 + (rem & 7)) * 256;
    int bc = (rem >> 3) * 256;

    int srow = lane >> 2;
    int scol = ((lane & 3) ^ ((srow >> 1) & 3)) * 8;
    const unsigned short* Ag0 = A + (size_t)(br + wave * 32 + srow) * K + scol;
    const unsigned short* Ag1 = Ag0 + (size_t)16 * K;
    const unsigned short* Bg0 = BT + (size_t)(bc + wave * 32 + srow) * K + scol;
    const unsigned short* Bg1 = Bg0 + (size_t)16 * K;

    f32x4 zero4 = {0.f, 0.f, 0.f, 0.f};
    f32x4 acc[8][4];
#pragma unroll
    for (int i = 0; i < 8; ++i)
#pragma unroll
        for (int j = 0; j < 4; ++j) acc[i][j] = zero4;

    auto stage = [&](int buf, int ko) {
        glds16(Ag0 + ko, &As[buf][wave * 32][0]);
        glds16(Ag1 + ko, &As[buf][wave * 32 + 16][0]);
        glds16(Bg0 + ko, &Bs[buf][wave * 32][0]);
        glds16(Bg1 + ko, &Bs[buf][wave * 32 + 16][0]);
    };

    int nt = K >> 5;
    stage(0, 0);
    stage(1, 32);
    stage(2, 64);
    int cq = (quad ^ ((lm >> 1) & 3)) << 3;  // swizzled column (shorts)
    for (int tt = 0; tt < nt; ++tt) {
        int cur = tt & 3;
        if (tt + 3 < nt) {
            stage((tt + 3) & 3, (tt + 3) << 5);
            asm volatile("s_waitcnt vmcnt(12)" ::: "memory");
        } else if (tt + 2 < nt) {
            asm volatile("s_waitcnt vmcnt(8)" ::: "memory");
        } else if (tt + 1 < nt) {
            asm volatile("s_waitcnt vmcnt(4)" ::: "memory");
        } else {
            asm volatile("s_waitcnt vmcnt(0)" ::: "memory");
        }
        __builtin_amdgcn_s_barrier();
        __builtin_amdgcn_sched_barrier(0);
        short8 af[8], bf[4];
#pragma unroll
        for (int i = 0; i < 8; ++i) af[i] = *(const short8*)&As[cur][wm + i * 16 + lm][cq];
#pragma unroll
        for (int j = 0; j < 4; ++j) bf[j] = *(const short8*)&Bs[cur][wn + j * 16 + lm][cq];
#pragma unroll
        for (int i = 0; i < 8; ++i)
#pragma unroll
            for (int j = 0; j < 4; ++j) acc[i][j] = MFMA16(af[i], bf[j], acc[i][j]);
        __builtin_amdgcn_sched_barrier(0);
        __builtin_amdgcn_s_barrier();
    }

#pragma unroll
    for (int i = 0; i < 8; ++i)
#pragma unroll
        for (int j = 0; j < 4; ++j) {
            int col = bc + wn + j * 16 + lm;
            float bv = bias ? bias[col] : 0.f;
#pragma unroll
            for (int r = 0; r < 4; ++r) {
                int row = br + wm + i * 16 + quad * 4 + r;
                float v = acc[i][j][r] + bv;
                if (act == 1) v = 0.5f * v * (1.f + erff(v * 0.70710678118f));
                size_t idx = (size_t)row * N + col;
                if (resid) v += resid[idx];
                if (cF32) ((float*)C)[idx] = v;
                else ((unsigned short*)C)[idx] = f2bf(v);
            }
        }
}

// -------- GEMM 128xBN (R1-proven): C = act(A @ BT^T + bias) + resid ---------
// Used for N=1024 shapes (proj, fc2) where a 256-wide tile would leave 3/4
// of the CUs idle, and for the fallback path. 2-buffer, depth-1 counted
// vmcnt, both-sides swizzle (conflicts measured 0).
template <int BN>
__global__ __launch_bounds__(256) void gemm_kernel(const unsigned short* __restrict__ A,
                                                   const unsigned short* __restrict__ BT,
                                                   const float* __restrict__ bias,
                                                   const float* __restrict__ resid,
                                                   void* __restrict__ C,
                                                   int M, int N, int K, int act, int cF32) {
    constexpr int NT = BN / 32;
    __shared__ __align__(16) unsigned short As[2][128][32];
    __shared__ __align__(16) unsigned short Bs[2][BN][32];
    int t = threadIdx.x, wave = t >> 6, lane = t & 63;
    int lm = lane & 15, quad = lane >> 4;
    int wm = (wave >> 1) * 64, wn = (wave & 1) * (BN / 2);

    int id = blockIdx.y * gridDim.x + blockIdx.x;
    int gsz = gridDim.x * 8;
    int grp = id / gsz, rem = id % gsz;
    int br = (grp * 8 + (rem & 7)) * 128;
    int bc = (rem >> 3) * BN;

    int srow = lane >> 2;
    int scol = ((lane & 3) ^ ((srow >> 1) & 3)) * 8;
    const unsigned short* Ag0 = A + (size_t)(br + wave * 32 + srow) * K + scol;
    const unsigned short* Ag1 = Ag0 + (size_t)16 * K;
    const unsigned short* Bg0 = BT + (size_t)(bc + wave * (BN / 4) + srow) * K + scol;
    const unsigned short* Bg1 = Bg0 + (size_t)16 * K;

    f32x4 zero4 = {0.f, 0.f, 0.f, 0.f};
    f32x4 acc[4][NT];
#pragma unroll
    for (int i = 0; i < 4; ++i)
#pragma unroll
        for (int j = 0; j < NT; ++j) acc[i][j] = zero4;

    auto stage = [&](int buf, int ko) {
        glds16(Ag0 + ko, &As[buf][wave * 32][0]);
        glds16(Ag1 + ko, &As[buf][wave * 32 + 16][0]);
        glds16(Bg0 + ko, &Bs[buf][wave * (BN / 4)][0]);
        if (BN == 128) glds16(Bg1 + ko, &Bs[buf][wave * (BN / 4) + 16][0]);
    };

    int nt = K >> 5;
    stage(0, 0);
    int rsw = (lm >> 1) & 3;
    int cq = (quad ^ rsw) << 3;
    for (int tt = 0; tt < nt; ++tt) {
        int cur = tt & 1;
        if (tt + 1 < nt) {
            stage(cur ^ 1, (tt + 1) << 5);
            if (BN == 128) asm volatile("s_waitcnt vmcnt(4)" ::: "memory");
            else           asm volatile("s_waitcnt vmcnt(3)" ::: "memory");
        } else {
            asm volatile("s_waitcnt vmcnt(0)" ::: "memory");
        }
        __builtin_amdgcn_s_barrier();
        __builtin_amdgcn_sched_barrier(0);
        short8 af[4], bf[NT];
#pragma unroll
        for (int i = 0; i < 4; ++i) af[i] = *(const short8*)&As[cur][wm + i * 16 + lm][cq];
#pragma unroll
        for (int j = 0; j < NT; ++j) bf[j] = *(const short8*)&Bs[cur][wn + j * 16 + lm][cq];
#pragma unroll
        for (int i = 0; i < 4; ++i)
#pragma unroll
            for (int j = 0; j < NT; ++j) acc[i][j] = MFMA16(af[i], bf[j], acc[i][j]);
        __builtin_amdgcn_sched_barrier(0);
        __builtin_amdgcn_s_barrier();
    }

#pragma unroll
    for (int i = 0; i < 4; ++i)
#pragma unroll
        for (int j = 0; j < NT; ++j) {
            int col = bc + wn + j * 16 + lm;
            float bv = bias ? bias[col] : 0.f;
#pragma unroll
            for (int r = 0; r < 4; ++r) {
                int row = br + wm + i * 16 + quad * 4 + r;
                float v = acc[i][j][r] + bv;
                if (act == 1) v = 0.5f * v * (1.f + erff(v * 0.70710678118f));
                size_t idx = (size_t)row * N + col;
                if (resid) v += resid[idx];
                if (cF32) ((float*)C)[idx] = v;
                else ((unsigned short*)C)[idx] = f2bf(v);
            }
        }
}

// -------- kvprep: repack K,V from qkv into glds16-ready swizzled layouts ----
__global__ __launch_bounds__(256) void kvprep_kernel(const unsigned short* __restrict__ qkv,
                                                     unsigned short* __restrict__ Kp,
                                                     unsigned short* __restrict__ Vt) {
    __shared__ unsigned short Vl[64][72];
    int t = threadIdx.x;
    int w = blockIdx.x, bh = blockIdx.y;
    int b = bh >> 4, h = bh & 15;
    int kt = w * 64;
    int sl = t >> 2, c = (t & 3) * 16;
    const unsigned short* src = qkv + (size_t)(b * 2048 + kt + sl) * 3072 + h * 64 + c;
    {
        uint4 k0 = *(const uint4*)(src + 1024);
        uint4 k1 = *(const uint4*)(src + 1024 + 8);
        int sw = sl & 7;
        int o0 = (c >> 3), o1 = o0 + 1;
        unsigned short* krow = Kp + ((size_t)bh * 2048 + kt + sl) * 64;
        *(uint4*)&krow[(o0 ^ sw) << 3] = k0;
        *(uint4*)&krow[(o1 ^ sw) << 3] = k1;
    }
    {
        uint4 v0 = *(const uint4*)(src + 2048);
        uint4 v1 = *(const uint4*)(src + 2048 + 8);
        *(uint4*)&Vl[sl][c] = v0;
        *(uint4*)&Vl[sl][c + 8] = v1;
    }
    __syncthreads();
    {
        int d = t >> 2, kc = (t & 3) * 16;
        unsigned short vv[16];
#pragma unroll
        for (int i = 0; i < 16; ++i) vv[i] = Vl[kc + i][d];
        int sw = d & 7;
        int ko0 = kc >> 3, ko1 = ko0 + 1;
        unsigned short* vrow = Vt + ((((size_t)bh * 32 + w) * 64) + d) * 64;
        *(uint4*)&vrow[(ko0 ^ sw) << 3] = *(uint4*)&vv[0];
        *(uint4*)&vrow[(ko1 ^ sw) << 3] = *(uint4*)&vv[8];
    }
}

// -------- attn2: glds16-staged K/V, fixed-shift softmax ---------------------
__global__ __launch_bounds__(256) void attn2_kernel(const unsigned short* __restrict__ qkv,
                                                    const unsigned short* __restrict__ Kp,
                                                    const unsigned short* __restrict__ Vt,
                                                    unsigned short* __restrict__ out) {
    __shared__ __align__(16) unsigned short Qs[64][72];
    __shared__ __align__(16) unsigned short Ks[4096];
    __shared__ __align__(16) unsigned short Vs[4096];
    __shared__ __align__(16) unsigned short Ps[4][16][72];

    int t = threadIdx.x, wave = t >> 6, lane = t & 63;
    int lm = lane & 15, quad = lane >> 4, k8 = quad * 8;
    int bh = blockIdx.y, b = bh >> 4, h = bh & 15;
    int q0 = blockIdx.x * 64;
    const unsigned short* base = qkv + (size_t)b * 2048 * 3072 + h * 64;

    {
        int r = t >> 2, c = (t & 3) * 16;
        const unsigned short* src = base + (size_t)(q0 + r) * 3072 + c;
        *(uint4*)&Qs[r][c] = *(const uint4*)src;
        *(uint4*)&Qs[r][c + 8] = *(const uint4*)(src + 8);
    }
    __syncthreads();
    short8 qa0 = *(const short8*)&Qs[wave * 16 + lm][k8];
    short8 qa1 = *(const short8*)&Qs[wave * 16 + lm][32 + k8];

    f32x4 zero4 = {0.f, 0.f, 0.f, 0.f};
    f32x4 oacc[4] = {zero4, zero4, zero4, zero4};
    float lsum[4] = {0.f, 0.f, 0.f, 0.f};

    for (int kt = 0; kt < 2048; kt += 64) {
        __syncthreads();
        {
            const unsigned short* kg = Kp + ((size_t)bh * 2048 + kt) * 64 + wave * 1024 + (lane << 3);
            unsigned short* kl = &Ks[wave * 1024];
            glds16(kg, kl);
            glds16(kg + 512, kl + 512);
            const unsigned short* vg = Vt + (((size_t)bh * 32 + (kt >> 6)) * 64) * 64 + wave * 1024 + (lane << 3);
            unsigned short* vl = &Vs[wave * 1024];
            glds16(vg, vl);
            glds16(vg + 512, vl + 512);
        }
        __syncthreads();

        f32x4 s[4];
#pragma unroll
        for (int nt = 0; nt < 4; ++nt) {
            int key = nt * 16 + lm;
            int swk = lm & 7;
            const unsigned short* krow = &Ks[key * 64];
            short8 kf0 = *(const short8*)&krow[(quad ^ swk) << 3];
            short8 kf1 = *(const short8*)&krow[((quad ^ swk) ^ 4) << 3];
            f32x4 a = zero4;
            a = MFMA16(qa0, kf0, a);
            a = MFMA16(qa1, kf1, a);
            s[nt] = a;
        }

#pragma unroll
        for (int r = 0; r < 4; ++r) {
            int row = quad * 4 + r;
            int sw = (row >> 1) & 7;
#pragma unroll
            for (int nt = 0; nt < 4; ++nt) {
                float p = __expf(s[nt][r] * 0.125f - 8.0f);
                lsum[r] += p;
                int g = (nt << 1) + (lm >> 3);
                Ps[wave][row][((g ^ sw) << 3) + (lm & 7)] = f2bf(p);
            }
        }

#pragma unroll
        for (int kh = 0; kh < 2; ++kh) {
            int pg = (kh << 2) + quad;
            short8 pa = *(const short8*)&Ps[wave][lm][(pg ^ ((lm >> 1) & 7)) << 3];
#pragma unroll
            for (int nt = 0; nt < 4; ++nt) {
                int d = nt * 16 + lm;
                short8 vf = *(const short8*)&Vs[d * 64 + ((pg ^ (lm & 7)) << 3)];
                oacc[nt] = MFMA16(pa, vf, oacc[nt]);
            }
        }
    }

#pragma unroll
    for (int r = 0; r < 4; ++r) {
        float l = lsum[r];
        l += __shfl_xor(l, 1); l += __shfl_xor(l, 2);
        l += __shfl_xor(l, 4); l += __shfl_xor(l, 8);
        float inv = 1.f / l;
        int qrow = q0 + wave * 16 + quad * 4 + r;
        size_t o = ((size_t)(b * 2048 + qrow)) * 1024 + h * 64;
#pragma unroll
        for (int nt = 0; nt < 4; ++nt) out[o + nt * 16 + lm] = f2bf(oacc[nt][r] * inv);
    }
}

// -------- fallback attention (round-6 proven, interleaved qkv) --------------
__global__ __launch_bounds__(256) void attn_kernel(const unsigned short* __restrict__ qkv,
                                                   unsigned short* __restrict__ out) {
    __shared__ __align__(16) unsigned short Qs[64][72];
    __shared__ __align__(16) unsigned short Ks[64][72];
    __shared__ __align__(16) unsigned short Vs[64][72];
    __shared__ __align__(16) unsigned short Ps[4][16][72];
    int t = threadIdx.x, wave = t >> 6, lane = t & 63;
    int lm = lane & 15, quad = lane >> 4, k8 = quad * 8;
    int bh = blockIdx.y, b = bh >> 4, h = bh & 15;
    int q0 = blockIdx.x * 64;
    const unsigned short* base = qkv + (size_t)b * 2048 * 3072 + h * 64;
    const unsigned short* kb = base + 1024;
    const unsigned short* vb = base + 2048;
    {
        int r = t >> 2, c = (t & 3) * 16;
        const unsigned short* src = base + (size_t)(q0 + r) * 3072 + c;
        *(uint4*)&Qs[r][c] = *(const uint4*)src;
        *(uint4*)&Qs[r][c + 8] = *(const uint4*)(src + 8);
    }
    __syncthreads();
    short8 qa0 = *(const short8*)&Qs[wave * 16 + lm][k8];
    short8 qa1 = *(const short8*)&Qs[wave * 16 + lm][32 + k8];
    f32x4 zero4 = {0.f, 0.f, 0.f, 0.f};
    f32x4 oacc[4] = {zero4, zero4, zero4, zero4};
    float lsum[4] = {0.f, 0.f, 0.f, 0.f};
    int sr = t >> 2, sc = (t & 3) * 16;
    for (int kt = 0; kt < 2048; kt += 64) {
        __syncthreads();
        {
            const unsigned short* ksrc = kb + (size_t)(kt + sr) * 3072 + sc;
            *(uint4*)&Ks[sr][sc] = *(const uint4*)ksrc;
            *(uint4*)&Ks[sr][sc + 8] = *(const uint4*)(ksrc + 8);
            const unsigned short* vsrc = vb + (size_t)(kt + sr) * 3072 + sc;
            unsigned short tv[16] __attribute__((aligned(16)));
            *(uint4*)&tv[0] = *(const uint4*)vsrc;
            *(uint4*)&tv[8] = *(const uint4*)(vsrc + 8);
            int kg = sr >> 3, kw = sr & 7;
#pragma unroll
            for (int j = 0; j < 16; ++j) {
                int d = sc + j;
                Vs[d][((kg ^ ((d >> 3) & 7)) << 3) + kw] = tv[j];
            }
        }
        __syncthreads();
        f32x4 s[4];
#pragma unroll
        for (int nt = 0; nt < 4; ++nt) {
            short8 kf0 = *(const short8*)&Ks[nt * 16 + lm][k8];
            short8 kf1 = *(const short8*)&Ks[nt * 16 + lm][32 + k8];
            f32x4 a = zero4;
            a = MFMA16(qa0, kf0, a);
            a = MFMA16(qa1, kf1, a);
            s[nt] = a;
        }
#pragma unroll
        for (int r = 0; r < 4; ++r) {
            int row = quad * 4 + r;
            int sw = (row >> 1) & 7;
#pragma unroll
            for (int nt = 0; nt < 4; ++nt) {
                float p = __expf(s[nt][r] * 0.125f - 8.0f);
                lsum[r] += p;
                int g = (nt << 1) + (lm >> 3);
                Ps[wave][row][((g ^ sw) << 3) + (lm & 7)] = f2bf(p);
            }
        }
#pragma unroll
        for (int kh = 0; kh < 2; ++kh) {
            int pg = (kh << 2) + quad;
            short8 pa = *(const short8*)&Ps[wave][lm][(pg ^ ((lm >> 1) & 7)) << 3];
#pragma unroll
            for (int nt = 0; nt < 4; ++nt) {
                int d = nt * 16 + lm;
                short8 vf = *(const short8*)&Vs[d][(pg ^ ((d >> 3) & 7)) << 3];
                oacc[nt] = MFMA16(pa, vf, oacc[nt]);
            }
        }
    }
#pragma unroll
    for (int r = 0; r < 4; ++r) {
        float l = lsum[r];
        l += __shfl_xor(l, 1); l += __shfl_xor(l, 2);
        l += __shfl_xor(l, 4); l += __shfl_xor(l, 8);
        float inv = 1.f / l;
        int qrow = q0 + wave * 16 + quad * 4 + r;
        size_t o = ((size_t)(b * 2048 + qrow)) * 1024 + h * 64;
#pragma unroll
        for (int nt = 0; nt < 4; ++nt) out[o + nt * 16 + lm] = f2bf(oacc[nt][r] * inv);
    }
}

extern "C" void kernel_launch(void* const* d_in, const int* in_sizes, int n_in,
                              void* d_out, int out_size, void* d_ws, size_t ws_size,
                              hipStream_t stream) {
    const float* x      = (const float*)d_in[0];
    const float* w_qkv  = (const float*)d_in[1];
    const float* w_proj = (const float*)d_in[2];
    const float* b_proj = (const float*)d_in[3];
    const float* w_fc1  = (const float*)d_in[4];
    const float* b_fc1  = (const float*)d_in[5];
    const float* w_fc2  = (const float*)d_in[6];
    const float* b_fc2  = (const float*)d_in[7];
    const float* g1     = (const float*)d_in[8];
    const float* be1    = (const float*)d_in[9];
    const float* g2     = (const float*)d_in[10];
    const float* be2    = (const float*)d_in[11];
    float* out = (float*)d_out;
    unsigned short* sb = (unsigned short*)d_out;  // bf16 scratch in d_out [0,8 MiB)

    char* ws = (char*)d_ws;
    unsigned short* wqkvT  = (unsigned short*)ws;
    unsigned short* wprojT = (unsigned short*)(ws + ((size_t)6u << 20));
    unsigned short* wfc1T  = (unsigned short*)(ws + ((size_t)8u << 20));
    unsigned short* wfc2T  = (unsigned short*)(ws + ((size_t)16u << 20));
    unsigned short* qkv    = (unsigned short*)(ws + ((size_t)24u << 20));

    // 0. merged weight convert+transpose
    convt_all_kernel<<<dim3(12288), dim3(256), 0, stream>>>(
        w_qkv, w_proj, w_fc1, w_fc2, wqkvT, wprojT, wfc1T, wfc2T);
    // 1. h = LN1(x) -> d_out bf16
    ln_kernel<<<dim3(4096), dim3(256), 0, stream>>>(x, g1, be1, sb);
    // 2. qkv = h @ w_qkv  (256^2 tile: grid 12x16 = 192 blocks)
    gemm256_kernel<<<dim3(12, 16), dim3(512), 0, stream>>>(
        sb, wqkvT, nullptr, nullptr, qkv, 4096, 3072, 1024, 0, 0);

    if (ws_size >= ((size_t)72u << 20)) {
        unsigned short* Kp = (unsigned short*)(ws + ((size_t)48u << 20));
        unsigned short* Vt = (unsigned short*)(ws + ((size_t)56u << 20));
        float*          x2 = (float*)(ws + ((size_t)24u << 20));
        unsigned short* m1 = (unsigned short*)(ws + ((size_t)40u << 20));
        // 3a. repack K,V into swizzled glds16-ready layouts
        kvprep_kernel<<<dim3(32, 32), dim3(256), 0, stream>>>(qkv, Kp, Vt);
        // 3b. attn -> d_out bf16 (h dead)
        attn2_kernel<<<dim3(32, 32), dim3(256), 0, stream>>>(qkv, Kp, Vt, sb);
        // 4. x2 = x + attn @ w_proj + b_proj  (N=1024: keep 128x64 kernel)
        gemm_kernel<64><<<dim3(16, 32), dim3(256), 0, stream>>>(
            sb, wprojT, b_proj, x, x2, 4096, 1024, 1024, 0, 1);
        // 5. h2 = LN2(x2) -> d_out bf16
        ln_kernel<<<dim3(4096), dim3(256), 0, stream>>>(x2, g2, be2, sb);
        // 6. m1 = gelu(h2 @ w_fc1 + b_fc1)  (256^2 tile: grid 16x16)
        gemm256_kernel<<<dim3(16, 16), dim3(512), 0, stream>>>(
            sb, wfc1T, b_fc1, nullptr, m1, 4096, 4096, 1024, 1, 0);
        // 7. out = x2 + m1 @ w_fc2 + b_fc2  (N=1024: keep 128x64 kernel)
        gemm_kernel<64><<<dim3(16, 32), dim3(256), 0, stream>>>(
            m1, wfc2T, b_fc2, x2, out, 4096, 1024, 4096, 0, 1);
    } else {
        float*          x2  = (float*)(ws + ((size_t)24u << 20));
        unsigned short* m1c = (unsigned short*)(ws + ((size_t)40u << 20));
        unsigned short* h2  = (unsigned short*)d_out + ((size_t)4u << 20);
        attn_kernel<<<dim3(32, 32), dim3(256), 0, stream>>>(qkv, sb);
        gemm_kernel<64><<<dim3(16, 32), dim3(256), 0, stream>>>(
            sb, wprojT, b_proj, x, x2, 4096, 1024, 1024, 0, 1);
        ln_kernel<<<dim3(4096), dim3(256), 0, stream>>>(x2, g2, be2, h2);
        for (int c = 0; c < 4; ++c) {
            size_t ro = (size_t)c * 1024;
            gemm_kernel<128><<<dim3(32, 8), dim3(256), 0, stream>>>(
                h2 + ro * 1024, wfc1T, b_fc1, nullptr, m1c, 1024, 4096, 1024, 1, 0);
            gemm_kernel<64><<<dim3(16, 8), dim3(256), 0, stream>>>(
                m1c, wfc2T, b_fc2, x2 + ro * 1024, out + ro * 1024, 1024, 1024, 4096, 0, 1);
        }
    }
}

// Round 4
// 426.606 us; speedup vs baseline: 1.0581x; 1.0581x over previous
//
#include <hip/hip_runtime.h>

typedef __attribute__((ext_vector_type(8))) short short8;
typedef __attribute__((ext_vector_type(4))) float f32x4;

#define MFMA16(a, b, c) __builtin_amdgcn_mfma_f32_16x16x32_bf16((a), (b), (c), 0, 0, 0)

static __device__ __forceinline__ unsigned short f2bf(float f) {
    unsigned int u = __float_as_uint(f);
    return (unsigned short)((u + 0x7fffu + ((u >> 16) & 1u)) >> 16);
}

// async 16B/lane global->LDS; LDS dest = wave-uniform base + lane*16
static __device__ __forceinline__ void glds16(const unsigned short* g, unsigned short* l) {
    __builtin_amdgcn_global_load_lds(
        (const __attribute__((address_space(1))) unsigned int*)g,
        (__attribute__((address_space(3))) unsigned int*)l, 16, 0, 0);
}

// -------- merged weight convert+transpose: W[K,N] fp32 -> WT[N,K] bf16 ------
__global__ __launch_bounds__(256) void convt_all_kernel(
    const float* __restrict__ w_qkv, const float* __restrict__ w_proj,
    const float* __restrict__ w_fc1, const float* __restrict__ w_fc2,
    unsigned short* __restrict__ wqkvT, unsigned short* __restrict__ wprojT,
    unsigned short* __restrict__ wfc1T, unsigned short* __restrict__ wfc2T) {
    __shared__ unsigned short Ts[32][33];
    int id = blockIdx.x;
    const float* W; unsigned short* WT; int K, N, bx, by;
    if (id < 3072)      { W = w_qkv;  WT = wqkvT;  K = 1024; N = 3072; bx = id % 96;  by = id / 96; }
    else if (id < 4096) { id -= 3072; W = w_proj; WT = wprojT; K = 1024; N = 1024; bx = id & 31; by = id >> 5; }
    else if (id < 8192) { id -= 4096; W = w_fc1;  WT = wfc1T;  K = 1024; N = 4096; bx = id & 127; by = id >> 7; }
    else                { id -= 8192; W = w_fc2;  WT = wfc2T;  K = 4096; N = 1024; bx = id & 31; by = id >> 5; }
    int t = threadIdx.x;
    int bk = by * 32, bn = bx * 32;
    int r = t >> 3, c = (t & 7) * 4;
    float4 w = *(const float4*)&W[(size_t)(bk + r) * N + bn + c];
    Ts[c + 0][r] = f2bf(w.x); Ts[c + 1][r] = f2bf(w.y);
    Ts[c + 2][r] = f2bf(w.z); Ts[c + 3][r] = f2bf(w.w);
    __syncthreads();
    ushort4 o;
    o.x = Ts[r][c]; o.y = Ts[r][c + 1]; o.z = Ts[r][c + 2]; o.w = Ts[r][c + 3];
    *(ushort4*)&WT[(size_t)(bn + r) * K + bk + c] = o;
}

// ---------------- LayerNorm: fp32 in -> bf16 out ----------------------------
__global__ __launch_bounds__(256) void ln_kernel(const float* __restrict__ x,
                                                 const float* __restrict__ g,
                                                 const float* __restrict__ be,
                                                 unsigned short* __restrict__ y) {
    int row = blockIdx.x;
    const float* xr = x + (size_t)row * 1024;
    unsigned short* yr = y + (size_t)row * 1024;
    int t = threadIdx.x;
    float v[4];
    float sum = 0.f, sq = 0.f;
#pragma unroll
    for (int i = 0; i < 4; ++i) {
        float f = xr[t + i * 256];
        v[i] = f; sum += f; sq += f * f;
    }
#pragma unroll
    for (int o = 32; o > 0; o >>= 1) { sum += __shfl_down(sum, o); sq += __shfl_down(sq, o); }
    __shared__ float red[8];
    int wave = t >> 6, lane = t & 63;
    if (lane == 0) { red[wave] = sum; red[4 + wave] = sq; }
    __syncthreads();
    sum = red[0] + red[1] + red[2] + red[3];
    sq  = red[4] + red[5] + red[6] + red[7];
    float mean = sum * (1.f / 1024.f);
    float var  = sq * (1.f / 1024.f) - mean * mean;
    float rstd = rsqrtf(var + 1e-5f);
#pragma unroll
    for (int i = 0; i < 4; ++i) {
        int c = t + i * 256;
        yr[c] = f2bf((v[i] - mean) * rstd * g[c] + be[c]);
    }
}

// phase sync macros (m201-style): reads+stage above barrier; counted waits;
// setprio around MFMA cluster (T5 -- pays only in phase-split schedules).
#define PHASE_MID                                            \
    __builtin_amdgcn_sched_barrier(0);                       \
    __builtin_amdgcn_s_barrier();                            \
    asm volatile("s_waitcnt lgkmcnt(0)" ::: "memory");       \
    __builtin_amdgcn_sched_barrier(0);                       \
    __builtin_amdgcn_s_setprio(1);
#define PHASE_END                                            \
    __builtin_amdgcn_s_setprio(0);                           \
    __builtin_amdgcn_sched_barrier(0);                       \
    __builtin_amdgcn_s_barrier();

// -------- GEMM 256x256, 4-phase/K-tile pipeline (m201-style) ----------------
// 512 thr = 8 waves (2M x 4N); per-wave 128x64 out (acc[8][4]); BK=64 as two
// 32-wide k-slices. LDS [2buf][2ks][256][32] for A and B = 128 KB.
// Per K-tile t (buf p), 4 phases, each {ds_read subtile; prefetch 1 half-tile;
// barrier; lgkm0; 16 MFMA; barrier}:
//  P1: read a0-3,b0-1 (12) | prefetch B-high(t+1)->q   | mfma a0-3 x b0-1
//  P2: read b2-3 (4)       | prefetch A-high(t+1)->q   | mfma a0-3 x b2-3
//  P3: read a4-7 (8)       | prefetch B-low (t+2)->p   | mfma a4-7 x b0-1
//  P4: (none)              | prefetch A-low (t+2)->p   | vmcnt(4); mfma a4-7 x b2-3
// Safety: B rows of buf p are last read in P2 (all waves past P2's end
// barrier before P3's prefetch issues); A rows last read in P3. vmcnt(4)
// at P4 leaves exactly the P3/P4-issued half-tiles (4 loads) in flight and
// confirms tile t+1 arrived -- never drains to 0 mid-loop (T3/T4).
// Both-sides XOR swizzle as verified in R1 (bank conflicts == 0).
// Requires M%256==0, N%256==0, gridDim.y%8==0, K%64==0, K>=192.
__global__ __launch_bounds__(512, 2) void gemm256_kernel(const unsigned short* __restrict__ A,
                                                         const unsigned short* __restrict__ BT,
                                                         const float* __restrict__ bias,
                                                         const float* __restrict__ resid,
                                                         void* __restrict__ C,
                                                         int M, int N, int K, int act, int cF32) {
    __shared__ __align__(16) unsigned short As[2][2][256][32];
    __shared__ __align__(16) unsigned short Bs[2][2][256][32];
    int t = threadIdx.x, wave = t >> 6, lane = t & 63;
    int lm = lane & 15, quad = lane >> 4;
    int wm = (wave >> 2) * 128, wn = (wave & 3) * 64;

    int id = blockIdx.y * gridDim.x + blockIdx.x;
    int gsz = gridDim.x * 8;
    int grp = id / gsz, rem = id % gsz;
    int br = (grp * 8 + (rem & 7)) * 256;
    int bc = (rem >> 3) * 256;

    int srow = lane >> 2;
    int scol = ((lane & 3) ^ ((srow >> 1) & 3)) * 8;
    const unsigned short* Ag = A + (size_t)(br + wave * 16 + srow) * K + scol;
    const unsigned short* Bg = BT + (size_t)(bc + wave * 16 + srow) * K + scol;

    // stage one half-tile (128 rows x 64 K) = 2 glds16/wave (ks0, ks1)
    auto stA = [&](int p_, int half, int ko) {
        const unsigned short* g = Ag + (size_t)half * 128 * K + ko;
        glds16(g,      &As[p_][0][half * 128 + wave * 16][0]);
        glds16(g + 32, &As[p_][1][half * 128 + wave * 16][0]);
    };
    auto stB = [&](int p_, int half, int ko) {
        const unsigned short* g = Bg + (size_t)half * 128 * K + ko;
        glds16(g,      &Bs[p_][0][half * 128 + wave * 16][0]);
        glds16(g + 32, &Bs[p_][1][half * 128 + wave * 16][0]);
    };

    f32x4 zero4 = {0.f, 0.f, 0.f, 0.f};
    f32x4 acc[8][4];
#pragma unroll
    for (int i = 0; i < 8; ++i)
#pragma unroll
        for (int j = 0; j < 4; ++j) acc[i][j] = zero4;

    int ntile = K >> 6;
    // prologue: tile0 complete + B-low/A-low of tile1; confirm tile0 arrived
    stA(0, 0, 0); stA(0, 1, 0); stB(0, 0, 0); stB(0, 1, 0);
    if (ntile > 1) { stB(1, 0, 64); stA(1, 0, 64); }
    __builtin_amdgcn_sched_barrier(0);
    if (ntile > 1) asm volatile("s_waitcnt vmcnt(4)" ::: "memory");
    else           asm volatile("s_waitcnt vmcnt(0)" ::: "memory");
    __builtin_amdgcn_s_barrier();

    int cq = (quad ^ ((lm >> 1) & 3)) << 3;  // swizzled column (shorts)

    for (int tt = 0; tt < ntile; ++tt) {
        int p = tt & 1, q = p ^ 1;
        int tko = tt * 64;
        // ---- P1 ----
        short8 aLo0[4], aLo1[4], bLo0[2], bLo1[2];
#pragma unroll
        for (int i = 0; i < 4; ++i) {
            aLo0[i] = *(const short8*)&As[p][0][wm + i * 16 + lm][cq];
            aLo1[i] = *(const short8*)&As[p][1][wm + i * 16 + lm][cq];
        }
#pragma unroll
        for (int j = 0; j < 2; ++j) {
            bLo0[j] = *(const short8*)&Bs[p][0][wn + j * 16 + lm][cq];
            bLo1[j] = *(const short8*)&Bs[p][1][wn + j * 16 + lm][cq];
        }
        if (tt + 1 < ntile) stB(q, 1, tko + 64);
        PHASE_MID;
#pragma unroll
        for (int i = 0; i < 4; ++i)
#pragma unroll
            for (int j = 0; j < 2; ++j) {
                acc[i][j] = MFMA16(aLo0[i], bLo0[j], acc[i][j]);
                acc[i][j] = MFMA16(aLo1[i], bLo1[j], acc[i][j]);
            }
        PHASE_END;
        // ---- P2 ----
        short8 bHi0[2], bHi1[2];
#pragma unroll
        for (int j = 0; j < 2; ++j) {
            bHi0[j] = *(const short8*)&Bs[p][0][wn + 32 + j * 16 + lm][cq];
            bHi1[j] = *(const short8*)&Bs[p][1][wn + 32 + j * 16 + lm][cq];
        }
        if (tt + 1 < ntile) stA(q, 1, tko + 64);
        PHASE_MID;
#pragma unroll
        for (int i = 0; i < 4; ++i)
#pragma unroll
            for (int j = 0; j < 2; ++j) {
                acc[i][j + 2] = MFMA16(aLo0[i], bHi0[j], acc[i][j + 2]);
                acc[i][j + 2] = MFMA16(aLo1[i], bHi1[j], acc[i][j + 2]);
            }
        PHASE_END;
        // ---- P3 ----
        short8 aHi0[4], aHi1[4];
#pragma unroll
        for (int i = 0; i < 4; ++i) {
            aHi0[i] = *(const short8*)&As[p][0][wm + 64 + i * 16 + lm][cq];
            aHi1[i] = *(const short8*)&As[p][1][wm + 64 + i * 16 + lm][cq];
        }
        if (tt + 2 < ntile) stB(p, 0, tko + 128);
        PHASE_MID;
#pragma unroll
        for (int i = 0; i < 4; ++i)
#pragma unroll
            for (int j = 0; j < 2; ++j) {
                acc[i + 4][j] = MFMA16(aHi0[i], bLo0[j], acc[i + 4][j]);
                acc[i + 4][j] = MFMA16(aHi1[i], bLo1[j], acc[i + 4][j]);
            }
        PHASE_END;
        // ---- P4 ----
        if (tt + 2 < ntile) stA(p, 0, tko + 128);
        __builtin_amdgcn_sched_barrier(0);
        if (tt + 2 < ntile) asm volatile("s_waitcnt vmcnt(4)" ::: "memory");
        else                asm volatile("s_waitcnt vmcnt(0)" ::: "memory");
        __builtin_amdgcn_s_barrier();
        asm volatile("s_waitcnt lgkmcnt(0)" ::: "memory");
        __builtin_amdgcn_sched_barrier(0);
        __builtin_amdgcn_s_setprio(1);
#pragma unroll
        for (int i = 0; i < 4; ++i)
#pragma unroll
            for (int j = 0; j < 2; ++j) {
                acc[i + 4][j + 2] = MFMA16(aHi0[i], bHi0[j], acc[i + 4][j + 2]);
                acc[i + 4][j + 2] = MFMA16(aHi1[i], bHi1[j], acc[i + 4][j + 2]);
            }
        PHASE_END;
    }

#pragma unroll
    for (int i = 0; i < 8; ++i)
#pragma unroll
        for (int j = 0; j < 4; ++j) {
            int col = bc + wn + j * 16 + lm;
            float bv = bias ? bias[col] : 0.f;
#pragma unroll
            for (int r = 0; r < 4; ++r) {
                int row = br + wm + i * 16 + quad * 4 + r;
                float v = acc[i][j][r] + bv;
                if (act == 1) v = 0.5f * v * (1.f + erff(v * 0.70710678118f));
                size_t idx = (size_t)row * N + col;
                if (resid) v += resid[idx];
                if (cF32) ((float*)C)[idx] = v;
                else ((unsigned short*)C)[idx] = f2bf(v);
            }
        }
}

// -------- GEMM 128xBN (R1-proven): C = act(A @ BT^T + bias) + resid ---------
// Used for N=1024 shapes (proj, fc2) and the fallback path. 2-buffer,
// depth-1 counted vmcnt, both-sides swizzle (conflicts measured 0).
template <int BN>
__global__ __launch_bounds__(256) void gemm_kernel(const unsigned short* __restrict__ A,
                                                   const unsigned short* __restrict__ BT,
                                                   const float* __restrict__ bias,
                                                   const float* __restrict__ resid,
                                                   void* __restrict__ C,
                                                   int M, int N, int K, int act, int cF32) {
    constexpr int NT = BN / 32;
    __shared__ __align__(16) unsigned short As[2][128][32];
    __shared__ __align__(16) unsigned short Bs[2][BN][32];
    int t = threadIdx.x, wave = t >> 6, lane = t & 63;
    int lm = lane & 15, quad = lane >> 4;
    int wm = (wave >> 1) * 64, wn = (wave & 1) * (BN / 2);

    int id = blockIdx.y * gridDim.x + blockIdx.x;
    int gsz = gridDim.x * 8;
    int grp = id / gsz, rem = id % gsz;
    int br = (grp * 8 + (rem & 7)) * 128;
    int bc = (rem >> 3) * BN;

    int srow = lane >> 2;
    int scol = ((lane & 3) ^ ((srow >> 1) & 3)) * 8;
    const unsigned short* Ag0 = A + (size_t)(br + wave * 32 + srow) * K + scol;
    const unsigned short* Ag1 = Ag0 + (size_t)16 * K;
    const unsigned short* Bg0 = BT + (size_t)(bc + wave * (BN / 4) + srow) * K + scol;
    const unsigned short* Bg1 = Bg0 + (size_t)16 * K;

    f32x4 zero4 = {0.f, 0.f, 0.f, 0.f};
    f32x4 acc[4][NT];
#pragma unroll
    for (int i = 0; i < 4; ++i)
#pragma unroll
        for (int j = 0; j < NT; ++j) acc[i][j] = zero4;

    auto stage = [&](int buf, int ko) {
        glds16(Ag0 + ko, &As[buf][wave * 32][0]);
        glds16(Ag1 + ko, &As[buf][wave * 32 + 16][0]);
        glds16(Bg0 + ko, &Bs[buf][wave * (BN / 4)][0]);
        if (BN == 128) glds16(Bg1 + ko, &Bs[buf][wave * (BN / 4) + 16][0]);
    };

    int nt = K >> 5;
    stage(0, 0);
    int rsw = (lm >> 1) & 3;
    int cq = (quad ^ rsw) << 3;
    for (int tt = 0; tt < nt; ++tt) {
        int cur = tt & 1;
        if (tt + 1 < nt) {
            stage(cur ^ 1, (tt + 1) << 5);
            if (BN == 128) asm volatile("s_waitcnt vmcnt(4)" ::: "memory");
            else           asm volatile("s_waitcnt vmcnt(3)" ::: "memory");
        } else {
            asm volatile("s_waitcnt vmcnt(0)" ::: "memory");
        }
        __builtin_amdgcn_s_barrier();
        __builtin_amdgcn_sched_barrier(0);
        short8 af[4], bf[NT];
#pragma unroll
        for (int i = 0; i < 4; ++i) af[i] = *(const short8*)&As[cur][wm + i * 16 + lm][cq];
#pragma unroll
        for (int j = 0; j < NT; ++j) bf[j] = *(const short8*)&Bs[cur][wn + j * 16 + lm][cq];
#pragma unroll
        for (int i = 0; i < 4; ++i)
#pragma unroll
            for (int j = 0; j < NT; ++j) acc[i][j] = MFMA16(af[i], bf[j], acc[i][j]);
        __builtin_amdgcn_sched_barrier(0);
        __builtin_amdgcn_s_barrier();
    }

#pragma unroll
    for (int i = 0; i < 4; ++i)
#pragma unroll
        for (int j = 0; j < NT; ++j) {
            int col = bc + wn + j * 16 + lm;
            float bv = bias ? bias[col] : 0.f;
#pragma unroll
            for (int r = 0; r < 4; ++r) {
                int row = br + wm + i * 16 + quad * 4 + r;
                float v = acc[i][j][r] + bv;
                if (act == 1) v = 0.5f * v * (1.f + erff(v * 0.70710678118f));
                size_t idx = (size_t)row * N + col;
                if (resid) v += resid[idx];
                if (cF32) ((float*)C)[idx] = v;
                else ((unsigned short*)C)[idx] = f2bf(v);
            }
        }
}

// -------- kvprep: repack K,V from qkv into glds16-ready swizzled layouts ----
__global__ __launch_bounds__(256) void kvprep_kernel(const unsigned short* __restrict__ qkv,
                                                     unsigned short* __restrict__ Kp,
                                                     unsigned short* __restrict__ Vt) {
    __shared__ unsigned short Vl[64][72];
    int t = threadIdx.x;
    int w = blockIdx.x, bh = blockIdx.y;
    int b = bh >> 4, h = bh & 15;
    int kt = w * 64;
    int sl = t >> 2, c = (t & 3) * 16;
    const unsigned short* src = qkv + (size_t)(b * 2048 + kt + sl) * 3072 + h * 64 + c;
    {
        uint4 k0 = *(const uint4*)(src + 1024);
        uint4 k1 = *(const uint4*)(src + 1024 + 8);
        int sw = sl & 7;
        int o0 = (c >> 3), o1 = o0 + 1;
        unsigned short* krow = Kp + ((size_t)bh * 2048 + kt + sl) * 64;
        *(uint4*)&krow[(o0 ^ sw) << 3] = k0;
        *(uint4*)&krow[(o1 ^ sw) << 3] = k1;
    }
    {
        uint4 v0 = *(const uint4*)(src + 2048);
        uint4 v1 = *(const uint4*)(src + 2048 + 8);
        *(uint4*)&Vl[sl][c] = v0;
        *(uint4*)&Vl[sl][c + 8] = v1;
    }
    __syncthreads();
    {
        int d = t >> 2, kc = (t & 3) * 16;
        unsigned short vv[16];
#pragma unroll
        for (int i = 0; i < 16; ++i) vv[i] = Vl[kc + i][d];
        int sw = d & 7;
        int ko0 = kc >> 3, ko1 = ko0 + 1;
        unsigned short* vrow = Vt + ((((size_t)bh * 32 + w) * 64) + d) * 64;
        *(uint4*)&vrow[(ko0 ^ sw) << 3] = *(uint4*)&vv[0];
        *(uint4*)&vrow[(ko1 ^ sw) << 3] = *(uint4*)&vv[8];
    }
}

// -------- attn2: glds16-staged K/V, fixed-shift softmax ---------------------
__global__ __launch_bounds__(256) void attn2_kernel(const unsigned short* __restrict__ qkv,
                                                    const unsigned short* __restrict__ Kp,
                                                    const unsigned short* __restrict__ Vt,
                                                    unsigned short* __restrict__ out) {
    __shared__ __align__(16) unsigned short Qs[64][72];
    __shared__ __align__(16) unsigned short Ks[4096];
    __shared__ __align__(16) unsigned short Vs[4096];
    __shared__ __align__(16) unsigned short Ps[4][16][72];

    int t = threadIdx.x, wave = t >> 6, lane = t & 63;
    int lm = lane & 15, quad = lane >> 4, k8 = quad * 8;
    int bh = blockIdx.y, b = bh >> 4, h = bh & 15;
    int q0 = blockIdx.x * 64;
    const unsigned short* base = qkv + (size_t)b * 2048 * 3072 + h * 64;

    {
        int r = t >> 2, c = (t & 3) * 16;
        const unsigned short* src = base + (size_t)(q0 + r) * 3072 + c;
        *(uint4*)&Qs[r][c] = *(const uint4*)src;
        *(uint4*)&Qs[r][c + 8] = *(const uint4*)(src + 8);
    }
    __syncthreads();
    short8 qa0 = *(const short8*)&Qs[wave * 16 + lm][k8];
    short8 qa1 = *(const short8*)&Qs[wave * 16 + lm][32 + k8];

    f32x4 zero4 = {0.f, 0.f, 0.f, 0.f};
    f32x4 oacc[4] = {zero4, zero4, zero4, zero4};
    float lsum[4] = {0.f, 0.f, 0.f, 0.f};

    for (int kt = 0; kt < 2048; kt += 64) {
        __syncthreads();
        {
            const unsigned short* kg = Kp + ((size_t)bh * 2048 + kt) * 64 + wave * 1024 + (lane << 3);
            unsigned short* kl = &Ks[wave * 1024];
            glds16(kg, kl);
            glds16(kg + 512, kl + 512);
            const unsigned short* vg = Vt + (((size_t)bh * 32 + (kt >> 6)) * 64) * 64 + wave * 1024 + (lane << 3);
            unsigned short* vl = &Vs[wave * 1024];
            glds16(vg, vl);
            glds16(vg + 512, vl + 512);
        }
        __syncthreads();

        f32x4 s[4];
#pragma unroll
        for (int nt = 0; nt < 4; ++nt) {
            int key = nt * 16 + lm;
            int swk = lm & 7;
            const unsigned short* krow = &Ks[key * 64];
            short8 kf0 = *(const short8*)&krow[(quad ^ swk) << 3];
            short8 kf1 = *(const short8*)&krow[((quad ^ swk) ^ 4) << 3];
            f32x4 a = zero4;
            a = MFMA16(qa0, kf0, a);
            a = MFMA16(qa1, kf1, a);
            s[nt] = a;
        }

#pragma unroll
        for (int r = 0; r < 4; ++r) {
            int row = quad * 4 + r;
            int sw = (row >> 1) & 7;
#pragma unroll
            for (int nt = 0; nt < 4; ++nt) {
                float p = __expf(s[nt][r] * 0.125f - 8.0f);
                lsum[r] += p;
                int g = (nt << 1) + (lm >> 3);
                Ps[wave][row][((g ^ sw) << 3) + (lm & 7)] = f2bf(p);
            }
        }

#pragma unroll
        for (int kh = 0; kh < 2; ++kh) {
            int pg = (kh << 2) + quad;
            short8 pa = *(const short8*)&Ps[wave][lm][(pg ^ ((lm >> 1) & 7)) << 3];
#pragma unroll
            for (int nt = 0; nt < 4; ++nt) {
                int d = nt * 16 + lm;
                short8 vf = *(const short8*)&Vs[d * 64 + ((pg ^ (lm & 7)) << 3)];
                oacc[nt] = MFMA16(pa, vf, oacc[nt]);
            }
        }
    }

#pragma unroll
    for (int r = 0; r < 4; ++r) {
        float l = lsum[r];
        l += __shfl_xor(l, 1); l += __shfl_xor(l, 2);
        l += __shfl_xor(l, 4); l += __shfl_xor(l, 8);
        float inv = 1.f / l;
        int qrow = q0 + wave * 16 + quad * 4 + r;
        size_t o = ((size_t)(b * 2048 + qrow)) * 1024 + h * 64;
#pragma unroll
        for (int nt = 0; nt < 4; ++nt) out[o + nt * 16 + lm] = f2bf(oacc[nt][r] * inv);
    }
}

// -------- fallback attention (round-6 proven, interleaved qkv) --------------
__global__ __launch_bounds__(256) void attn_kernel(const unsigned short* __restrict__ qkv,
                                                   unsigned short* __restrict__ out) {
    __shared__ __align__(16) unsigned short Qs[64][72];
    __shared__ __align__(16) unsigned short Ks[64][72];
    __shared__ __align__(16) unsigned short Vs[64][72];
    __shared__ __align__(16) unsigned short Ps[4][16][72];
    int t = threadIdx.x, wave = t >> 6, lane = t & 63;
    int lm = lane & 15, quad = lane >> 4, k8 = quad * 8;
    int bh = blockIdx.y, b = bh >> 4, h = bh & 15;
    int q0 = blockIdx.x * 64;
    const unsigned short* base = qkv + (size_t)b * 2048 * 3072 + h * 64;
    const unsigned short* kb = base + 1024;
    const unsigned short* vb = base + 2048;
    {
        int r = t >> 2, c = (t & 3) * 16;
        const unsigned short* src = base + (size_t)(q0 + r) * 3072 + c;
        *(uint4*)&Qs[r][c] = *(const uint4*)src;
        *(uint4*)&Qs[r][c + 8] = *(const uint4*)(src + 8);
    }
    __syncthreads();
    short8 qa0 = *(const short8*)&Qs[wave * 16 + lm][k8];
    short8 qa1 = *(const short8*)&Qs[wave * 16 + lm][32 + k8];
    f32x4 zero4 = {0.f, 0.f, 0.f, 0.f};
    f32x4 oacc[4] = {zero4, zero4, zero4, zero4};
    float lsum[4] = {0.f, 0.f, 0.f, 0.f};
    int sr = t >> 2, sc = (t & 3) * 16;
    for (int kt = 0; kt < 2048; kt += 64) {
        __syncthreads();
        {
            const unsigned short* ksrc = kb + (size_t)(kt + sr) * 3072 + sc;
            *(uint4*)&Ks[sr][sc] = *(const uint4*)ksrc;
            *(uint4*)&Ks[sr][sc + 8] = *(const uint4*)(ksrc + 8);
            const unsigned short* vsrc = vb + (size_t)(kt + sr) * 3072 + sc;
            unsigned short tv[16] __attribute__((aligned(16)));
            *(uint4*)&tv[0] = *(const uint4*)vsrc;
            *(uint4*)&tv[8] = *(const uint4*)(vsrc + 8);
            int kg = sr >> 3, kw = sr & 7;
#pragma unroll
            for (int j = 0; j < 16; ++j) {
                int d = sc + j;
                Vs[d][((kg ^ ((d >> 3) & 7)) << 3) + kw] = tv[j];
            }
        }
        __syncthreads();
        f32x4 s[4];
#pragma unroll
        for (int nt = 0; nt < 4; ++nt) {
            short8 kf0 = *(const short8*)&Ks[nt * 16 + lm][k8];
            short8 kf1 = *(const short8*)&Ks[nt * 16 + lm][32 + k8];
            f32x4 a = zero4;
            a = MFMA16(qa0, kf0, a);
            a = MFMA16(qa1, kf1, a);
            s[nt] = a;
        }
#pragma unroll
        for (int r = 0; r < 4; ++r) {
            int row = quad * 4 + r;
            int sw = (row >> 1) & 7;
#pragma unroll
            for (int nt = 0; nt < 4; ++nt) {
                float p = __expf(s[nt][r] * 0.125f - 8.0f);
                lsum[r] += p;
                int g = (nt << 1) + (lm >> 3);
                Ps[wave][row][((g ^ sw) << 3) + (lm & 7)] = f2bf(p);
            }
        }
#pragma unroll
        for (int kh = 0; kh < 2; ++kh) {
            int pg = (kh << 2) + quad;
            short8 pa = *(const short8*)&Ps[wave][lm][(pg ^ ((lm >> 1) & 7)) << 3];
#pragma unroll
            for (int nt = 0; nt < 4; ++nt) {
                int d = nt * 16 + lm;
                short8 vf = *(const short8*)&Vs[d][(pg ^ ((d >> 3) & 7)) << 3];
                oacc[nt] = MFMA16(pa, vf, oacc[nt]);
            }
        }
    }
#pragma unroll
    for (int r = 0; r < 4; ++r) {
        float l = lsum[r];
        l += __shfl_xor(l, 1); l += __shfl_xor(l, 2);
        l += __shfl_xor(l, 4); l += __shfl_xor(l, 8);
        float inv = 1.f / l;
        int qrow = q0 + wave * 16 + quad * 4 + r;
        size_t o = ((size_t)(b * 2048 + qrow)) * 1024 + h * 64;
#pragma unroll
        for (int nt = 0; nt < 4; ++nt) out[o + nt * 16 + lm] = f2bf(oacc[nt][r] * inv);
    }
}

extern "C" void kernel_launch(void* const* d_in, const int* in_sizes, int n_in,
                              void* d_out, int out_size, void* d_ws, size_t ws_size,
                              hipStream_t stream) {
    const float* x      = (const float*)d_in[0];
    const float* w_qkv  = (const float*)d_in[1];
    const float* w_proj = (const float*)d_in[2];
    const float* b_proj = (const float*)d_in[3];
    const float* w_fc1  = (const float*)d_in[4];
    const float* b_fc1  = (const float*)d_in[5];
    const float* w_fc2  = (const float*)d_in[6];
    const float* b_fc2  = (const float*)d_in[7];
    const float* g1     = (const float*)d_in[8];
    const float* be1    = (const float*)d_in[9];
    const float* g2     = (const float*)d_in[10];
    const float* be2    = (const float*)d_in[11];
    float* out = (float*)d_out;
    unsigned short* sb = (unsigned short*)d_out;  // bf16 scratch in d_out [0,8 MiB)

    char* ws = (char*)d_ws;
    unsigned short* wqkvT  = (unsigned short*)ws;
    unsigned short* wprojT = (unsigned short*)(ws + ((size_t)6u << 20));
    unsigned short* wfc1T  = (unsigned short*)(ws + ((size_t)8u << 20));
    unsigned short* wfc2T  = (unsigned short*)(ws + ((size_t)16u << 20));
    unsigned short* qkv    = (unsigned short*)(ws + ((size_t)24u << 20));

    // 0. merged weight convert+transpose
    convt_all_kernel<<<dim3(12288), dim3(256), 0, stream>>>(
        w_qkv, w_proj, w_fc1, w_fc2, wqkvT, wprojT, wfc1T, wfc2T);
    // 1. h = LN1(x) -> d_out bf16
    ln_kernel<<<dim3(4096), dim3(256), 0, stream>>>(x, g1, be1, sb);
    // 2. qkv = h @ w_qkv  (256^2 4-phase: grid 12x16 = 192 blocks)
    gemm256_kernel<<<dim3(12, 16), dim3(512), 0, stream>>>(
        sb, wqkvT, nullptr, nullptr, qkv, 4096, 3072, 1024, 0, 0);

    if (ws_size >= ((size_t)72u << 20)) {
        unsigned short* Kp = (unsigned short*)(ws + ((size_t)48u << 20));
        unsigned short* Vt = (unsigned short*)(ws + ((size_t)56u << 20));
        float*          x2 = (float*)(ws + ((size_t)24u << 20));
        unsigned short* m1 = (unsigned short*)(ws + ((size_t)40u << 20));
        // 3a. repack K,V into swizzled glds16-ready layouts
        kvprep_kernel<<<dim3(32, 32), dim3(256), 0, stream>>>(qkv, Kp, Vt);
        // 3b. attn -> d_out bf16 (h dead)
        attn2_kernel<<<dim3(32, 32), dim3(256), 0, stream>>>(qkv, Kp, Vt, sb);
        // 4. x2 = x + attn @ w_proj + b_proj  (N=1024: keep 128x64 kernel)
        gemm_kernel<64><<<dim3(16, 32), dim3(256), 0, stream>>>(
            sb, wprojT, b_proj, x, x2, 4096, 1024, 1024, 0, 1);
        // 5. h2 = LN2(x2) -> d_out bf16
        ln_kernel<<<dim3(4096), dim3(256), 0, stream>>>(x2, g2, be2, sb);
        // 6. m1 = gelu(h2 @ w_fc1 + b_fc1)  (256^2 4-phase: grid 16x16)
        gemm256_kernel<<<dim3(16, 16), dim3(512), 0, stream>>>(
            sb, wfc1T, b_fc1, nullptr, m1, 4096, 4096, 1024, 1, 0);
        // 7. out = x2 + m1 @ w_fc2 + b_fc2  (N=1024: keep 128x64 kernel)
        gemm_kernel<64><<<dim3(16, 32), dim3(256), 0, stream>>>(
            m1, wfc2T, b_fc2, x2, out, 4096, 1024, 4096, 0, 1);
    } else {
        float*          x2  = (float*)(ws + ((size_t)24u << 20));
        unsigned short* m1c = (unsigned short*)(ws + ((size_t)40u << 20));
        unsigned short* h2  = (unsigned short*)d_out + ((size_t)4u << 20);
        attn_kernel<<<dim3(32, 32), dim3(256), 0, stream>>>(qkv, sb);
        gemm_kernel<64><<<dim3(16, 32), dim3(256), 0, stream>>>(
            sb, wprojT, b_proj, x, x2, 4096, 1024, 1024, 0, 1);
        ln_kernel<<<dim3(4096), dim3(256), 0, stream>>>(x2, g2, be2, h2);
        for (int c = 0; c < 4; ++c) {
            size_t ro = (size_t)c * 1024;
            gemm_kernel<128><<<dim3(32, 8), dim3(256), 0, stream>>>(
                h2 + ro * 1024, wfc1T, b_fc1, nullptr, m1c, 1024, 4096, 1024, 1, 0);
            gemm_kernel<64><<<dim3(16, 8), dim3(256), 0, stream>>>(
                m1c, wfc2T, b_fc2, x2 + ro * 1024, out + ro * 1024, 1024, 1024, 4096, 0, 1);
        }
    }
}

// Round 5
// 396.305 us; speedup vs baseline: 1.1390x; 1.0765x over previous
//
#include <hip/hip_runtime.h>

typedef __attribute__((ext_vector_type(8))) short short8;
typedef __attribute__((ext_vector_type(4))) float f32x4;

#define MFMA16(a, b, c) __builtin_amdgcn_mfma_f32_16x16x32_bf16((a), (b), (c), 0, 0, 0)

static __device__ __forceinline__ unsigned short f2bf(float f) {
    unsigned int u = __float_as_uint(f);
    return (unsigned short)((u + 0x7fffu + ((u >> 16) & 1u)) >> 16);
}

// async 16B/lane global->LDS; LDS dest = wave-uniform base + lane*16
static __device__ __forceinline__ void glds16(const unsigned short* g, unsigned short* l) {
    __builtin_amdgcn_global_load_lds(
        (const __attribute__((address_space(1))) unsigned int*)g,
        (__attribute__((address_space(3))) unsigned int*)l, 16, 0, 0);
}

// -------- merged weight convert+transpose: W[K,N] fp32 -> WT[N,K] bf16 ------
__global__ __launch_bounds__(256) void convt_all_kernel(
    const float* __restrict__ w_qkv, const float* __restrict__ w_proj,
    const float* __restrict__ w_fc1, const float* __restrict__ w_fc2,
    unsigned short* __restrict__ wqkvT, unsigned short* __restrict__ wprojT,
    unsigned short* __restrict__ wfc1T, unsigned short* __restrict__ wfc2T) {
    __shared__ unsigned short Ts[32][33];
    int id = blockIdx.x;
    const float* W; unsigned short* WT; int K, N, bx, by;
    if (id < 3072)      { W = w_qkv;  WT = wqkvT;  K = 1024; N = 3072; bx = id % 96;  by = id / 96; }
    else if (id < 4096) { id -= 3072; W = w_proj; WT = wprojT; K = 1024; N = 1024; bx = id & 31; by = id >> 5; }
    else if (id < 8192) { id -= 4096; W = w_fc1;  WT = wfc1T;  K = 1024; N = 4096; bx = id & 127; by = id >> 7; }
    else                { id -= 8192; W = w_fc2;  WT = wfc2T;  K = 4096; N = 1024; bx = id & 31; by = id >> 5; }
    int t = threadIdx.x;
    int bk = by * 32, bn = bx * 32;
    int r = t >> 3, c = (t & 7) * 4;
    float4 w = *(const float4*)&W[(size_t)(bk + r) * N + bn + c];
    Ts[c + 0][r] = f2bf(w.x); Ts[c + 1][r] = f2bf(w.y);
    Ts[c + 2][r] = f2bf(w.z); Ts[c + 3][r] = f2bf(w.w);
    __syncthreads();
    ushort4 o;
    o.x = Ts[r][c]; o.y = Ts[r][c + 1]; o.z = Ts[r][c + 2]; o.w = Ts[r][c + 3];
    *(ushort4*)&WT[(size_t)(bn + r) * K + bk + c] = o;
}

// ---------------- LayerNorm: fp32 in -> bf16 out ----------------------------
__global__ __launch_bounds__(256) void ln_kernel(const float* __restrict__ x,
                                                 const float* __restrict__ g,
                                                 const float* __restrict__ be,
                                                 unsigned short* __restrict__ y) {
    int row = blockIdx.x;
    const float* xr = x + (size_t)row * 1024;
    unsigned short* yr = y + (size_t)row * 1024;
    int t = threadIdx.x;
    float v[4];
    float sum = 0.f, sq = 0.f;
#pragma unroll
    for (int i = 0; i < 4; ++i) {
        float f = xr[t + i * 256];
        v[i] = f; sum += f; sq += f * f;
    }
#pragma unroll
    for (int o = 32; o > 0; o >>= 1) { sum += __shfl_down(sum, o); sq += __shfl_down(sq, o); }
    __shared__ float red[8];
    int wave = t >> 6, lane = t & 63;
    if (lane == 0) { red[wave] = sum; red[4 + wave] = sq; }
    __syncthreads();
    sum = red[0] + red[1] + red[2] + red[3];
    sq  = red[4] + red[5] + red[6] + red[7];
    float mean = sum * (1.f / 1024.f);
    float var  = sq * (1.f / 1024.f) - mean * mean;
    float rstd = rsqrtf(var + 1e-5f);
#pragma unroll
    for (int i = 0; i < 4; ++i) {
        int c = t + i * 256;
        yr[c] = f2bf((v[i] - mean) * rstd * g[c] + be[c]);
    }
}

// phase sync macros (m201-style): reads+stage above barrier; counted waits;
// setprio around MFMA cluster (T5 -- pays only in phase-split schedules).
#define PHASE_MID                                            \
    __builtin_amdgcn_sched_barrier(0);                       \
    __builtin_amdgcn_s_barrier();                            \
    asm volatile("s_waitcnt lgkmcnt(0)" ::: "memory");       \
    __builtin_amdgcn_sched_barrier(0);                       \
    __builtin_amdgcn_s_setprio(1);
#define PHASE_END                                            \
    __builtin_amdgcn_s_setprio(0);                           \
    __builtin_amdgcn_sched_barrier(0);                       \
    __builtin_amdgcn_s_barrier();

// -------- GEMM 256x256, 4-phase/K-tile pipeline (R4-proven) -----------------
__global__ __launch_bounds__(512, 2) void gemm256_kernel(const unsigned short* __restrict__ A,
                                                         const unsigned short* __restrict__ BT,
                                                         const float* __restrict__ bias,
                                                         const float* __restrict__ resid,
                                                         void* __restrict__ C,
                                                         int M, int N, int K, int act, int cF32) {
    __shared__ __align__(16) unsigned short As[2][2][256][32];
    __shared__ __align__(16) unsigned short Bs[2][2][256][32];
    int t = threadIdx.x, wave = t >> 6, lane = t & 63;
    int lm = lane & 15, quad = lane >> 4;
    int wm = (wave >> 2) * 128, wn = (wave & 3) * 64;

    int id = blockIdx.y * gridDim.x + blockIdx.x;
    int gsz = gridDim.x * 8;
    int grp = id / gsz, rem = id % gsz;
    int br = (grp * 8 + (rem & 7)) * 256;
    int bc = (rem >> 3) * 256;

    int srow = lane >> 2;
    int scol = ((lane & 3) ^ ((srow >> 1) & 3)) * 8;
    const unsigned short* Ag = A + (size_t)(br + wave * 16 + srow) * K + scol;
    const unsigned short* Bg = BT + (size_t)(bc + wave * 16 + srow) * K + scol;

    auto stA = [&](int p_, int half, int ko) {
        const unsigned short* g = Ag + (size_t)half * 128 * K + ko;
        glds16(g,      &As[p_][0][half * 128 + wave * 16][0]);
        glds16(g + 32, &As[p_][1][half * 128 + wave * 16][0]);
    };
    auto stB = [&](int p_, int half, int ko) {
        const unsigned short* g = Bg + (size_t)half * 128 * K + ko;
        glds16(g,      &Bs[p_][0][half * 128 + wave * 16][0]);
        glds16(g + 32, &Bs[p_][1][half * 128 + wave * 16][0]);
    };

    f32x4 zero4 = {0.f, 0.f, 0.f, 0.f};
    f32x4 acc[8][4];
#pragma unroll
    for (int i = 0; i < 8; ++i)
#pragma unroll
        for (int j = 0; j < 4; ++j) acc[i][j] = zero4;

    int ntile = K >> 6;
    stA(0, 0, 0); stA(0, 1, 0); stB(0, 0, 0); stB(0, 1, 0);
    if (ntile > 1) { stB(1, 0, 64); stA(1, 0, 64); }
    __builtin_amdgcn_sched_barrier(0);
    if (ntile > 1) asm volatile("s_waitcnt vmcnt(4)" ::: "memory");
    else           asm volatile("s_waitcnt vmcnt(0)" ::: "memory");
    __builtin_amdgcn_s_barrier();

    int cq = (quad ^ ((lm >> 1) & 3)) << 3;

    for (int tt = 0; tt < ntile; ++tt) {
        int p = tt & 1, q = p ^ 1;
        int tko = tt * 64;
        // ---- P1 ----
        short8 aLo0[4], aLo1[4], bLo0[2], bLo1[2];
#pragma unroll
        for (int i = 0; i < 4; ++i) {
            aLo0[i] = *(const short8*)&As[p][0][wm + i * 16 + lm][cq];
            aLo1[i] = *(const short8*)&As[p][1][wm + i * 16 + lm][cq];
        }
#pragma unroll
        for (int j = 0; j < 2; ++j) {
            bLo0[j] = *(const short8*)&Bs[p][0][wn + j * 16 + lm][cq];
            bLo1[j] = *(const short8*)&Bs[p][1][wn + j * 16 + lm][cq];
        }
        if (tt + 1 < ntile) stB(q, 1, tko + 64);
        PHASE_MID;
#pragma unroll
        for (int i = 0; i < 4; ++i)
#pragma unroll
            for (int j = 0; j < 2; ++j) {
                acc[i][j] = MFMA16(aLo0[i], bLo0[j], acc[i][j]);
                acc[i][j] = MFMA16(aLo1[i], bLo1[j], acc[i][j]);
            }
        PHASE_END;
        // ---- P2 ----
        short8 bHi0[2], bHi1[2];
#pragma unroll
        for (int j = 0; j < 2; ++j) {
            bHi0[j] = *(const short8*)&Bs[p][0][wn + 32 + j * 16 + lm][cq];
            bHi1[j] = *(const short8*)&Bs[p][1][wn + 32 + j * 16 + lm][cq];
        }
        if (tt + 1 < ntile) stA(q, 1, tko + 64);
        PHASE_MID;
#pragma unroll
        for (int i = 0; i < 4; ++i)
#pragma unroll
            for (int j = 0; j < 2; ++j) {
                acc[i][j + 2] = MFMA16(aLo0[i], bHi0[j], acc[i][j + 2]);
                acc[i][j + 2] = MFMA16(aLo1[i], bHi1[j], acc[i][j + 2]);
            }
        PHASE_END;
        // ---- P3 ----
        short8 aHi0[4], aHi1[4];
#pragma unroll
        for (int i = 0; i < 4; ++i) {
            aHi0[i] = *(const short8*)&As[p][0][wm + 64 + i * 16 + lm][cq];
            aHi1[i] = *(const short8*)&As[p][1][wm + 64 + i * 16 + lm][cq];
        }
        if (tt + 2 < ntile) stB(p, 0, tko + 128);
        PHASE_MID;
#pragma unroll
        for (int i = 0; i < 4; ++i)
#pragma unroll
            for (int j = 0; j < 2; ++j) {
                acc[i + 4][j] = MFMA16(aHi0[i], bLo0[j], acc[i + 4][j]);
                acc[i + 4][j] = MFMA16(aHi1[i], bLo1[j], acc[i + 4][j]);
            }
        PHASE_END;
        // ---- P4 ----
        if (tt + 2 < ntile) stA(p, 0, tko + 128);
        __builtin_amdgcn_sched_barrier(0);
        if (tt + 2 < ntile) asm volatile("s_waitcnt vmcnt(4)" ::: "memory");
        else                asm volatile("s_waitcnt vmcnt(0)" ::: "memory");
        __builtin_amdgcn_s_barrier();
        asm volatile("s_waitcnt lgkmcnt(0)" ::: "memory");
        __builtin_amdgcn_sched_barrier(0);
        __builtin_amdgcn_s_setprio(1);
#pragma unroll
        for (int i = 0; i < 4; ++i)
#pragma unroll
            for (int j = 0; j < 2; ++j) {
                acc[i + 4][j + 2] = MFMA16(aHi0[i], bHi0[j], acc[i + 4][j + 2]);
                acc[i + 4][j + 2] = MFMA16(aHi1[i], bHi1[j], acc[i + 4][j + 2]);
            }
        PHASE_END;
    }

#pragma unroll
    for (int i = 0; i < 8; ++i)
#pragma unroll
        for (int j = 0; j < 4; ++j) {
            int col = bc + wn + j * 16 + lm;
            float bv = bias ? bias[col] : 0.f;
#pragma unroll
            for (int r = 0; r < 4; ++r) {
                int row = br + wm + i * 16 + quad * 4 + r;
                float v = acc[i][j][r] + bv;
                if (act == 1) v = 0.5f * v * (1.f + erff(v * 0.70710678118f));
                size_t idx = (size_t)row * N + col;
                if (resid) v += resid[idx];
                if (cF32) ((float*)C)[idx] = v;
                else ((unsigned short*)C)[idx] = f2bf(v);
            }
        }
}

// -------- GEMM 128x64, 2-phase/K-tile, ring-3, stage-2-ahead ----------------
// For N=1024 shapes (proj, fc2 -- fc2's K=4096 A-stream is HBM-heavy, needs
// deep cover). 256 thr = 4 waves (2M x 2N), per-wave 64x32 (acc[4][2]).
// BK=64 (2 k-slices). LDS ring-3: 3 x (A 16KB + B 8KB) = 72KB -> 2 blk/CU.
// Per K-tile t (buf p=t%3): P1 {ds_read a(8)+b0(2); stage A(t+2); bar;
// lgkm0; 8 MFMA; bar}  P2 {ds_read b1(2); stage B(t+2); vmcnt(6); bar;
// lgkm0; 8 MFMA; bar}. vmcnt(6) leaves exactly A(t+2)+B(t+2) in flight and
// confirms tile t+1 arrived (staged one full tile earlier) -- loads get a
// whole K-tile of latency cover; never drains mid-loop (T3/T4). Retire
// proof: A[(t+2)%3] last read in tile t-1's P1; B[(t+2)%3] in t-1's P2;
// both barrier-separated from the stage. Both-sides XOR swizzle (R1-
// verified, conflicts==0). Requires gridDim.y%8==0, K%64==0.
__global__ __launch_bounds__(256) void gemm64_4ph(const unsigned short* __restrict__ A,
                                                  const unsigned short* __restrict__ BT,
                                                  const float* __restrict__ bias,
                                                  const float* __restrict__ resid,
                                                  void* __restrict__ C,
                                                  int M, int N, int K, int act, int cF32) {
    __shared__ __align__(16) unsigned short As[3][2][128][32];
    __shared__ __align__(16) unsigned short Bs[3][2][64][32];
    int t = threadIdx.x, wave = t >> 6, lane = t & 63;
    int lm = lane & 15, quad = lane >> 4;
    int wm = (wave >> 1) * 64, wn = (wave & 1) * 32;

    int id = blockIdx.y * gridDim.x + blockIdx.x;
    int gsz = gridDim.x * 8;
    int grp = id / gsz, rem = id % gsz;
    int br = (grp * 8 + (rem & 7)) * 128;
    int bc = (rem >> 3) * 64;

    int srow = lane >> 2;
    int scol = ((lane & 3) ^ ((srow >> 1) & 3)) * 8;
    const unsigned short* Ag = A + (size_t)(br + wave * 16 + srow) * K + scol;
    const unsigned short* Bg = BT + (size_t)(bc + wave * 16 + srow) * K + scol;

    // A tile 128x64 = 4 glds16/wave (2 row-halves x 2 k-slices)
    auto stA = [&](int b, int ko) {
#pragma unroll
        for (int l = 0; l < 4; ++l)
            glds16(Ag + (size_t)(l >> 1) * 64 * K + (l & 1) * 32 + ko,
                   &As[b][l & 1][(l >> 1) * 64 + wave * 16][0]);
    };
    // B tile 64x64 = 2 glds16/wave (2 k-slices)
    auto stB = [&](int b, int ko) {
#pragma unroll
        for (int l = 0; l < 2; ++l)
            glds16(Bg + (size_t)l * 32 + ko, &Bs[b][l][wave * 16][0]);
    };

    f32x4 zero4 = {0.f, 0.f, 0.f, 0.f};
    f32x4 acc[4][2];
#pragma unroll
    for (int i = 0; i < 4; ++i) { acc[i][0] = zero4; acc[i][1] = zero4; }

    int nt = K >> 6;
    stA(0, 0); stB(0, 0);
    if (nt > 1) { stA(1, 64); stB(1, 64); }
    __builtin_amdgcn_sched_barrier(0);
    if (nt > 1) asm volatile("s_waitcnt vmcnt(6)" ::: "memory");
    else        asm volatile("s_waitcnt vmcnt(0)" ::: "memory");
    __builtin_amdgcn_s_barrier();

    int cq = (quad ^ ((lm >> 1) & 3)) << 3;

    int p = 0;
    for (int tt = 0; tt < nt; ++tt) {
        int pn = p + 1; if (pn == 3) pn = 0;
        int pnn = pn + 1; if (pnn == 3) pnn = 0;
        // ---- P1 ----
        short8 a0[4], a1[4], b00, b01;
#pragma unroll
        for (int i = 0; i < 4; ++i) {
            a0[i] = *(const short8*)&As[p][0][wm + i * 16 + lm][cq];
            a1[i] = *(const short8*)&As[p][1][wm + i * 16 + lm][cq];
        }
        b00 = *(const short8*)&Bs[p][0][wn + lm][cq];
        b01 = *(const short8*)&Bs[p][1][wn + lm][cq];
        if (tt + 2 < nt) stA(pnn, (tt + 2) << 6);
        PHASE_MID;
#pragma unroll
        for (int i = 0; i < 4; ++i) {
            acc[i][0] = MFMA16(a0[i], b00, acc[i][0]);
            acc[i][0] = MFMA16(a1[i], b01, acc[i][0]);
        }
        PHASE_END;
        // ---- P2 ----
        short8 b10 = *(const short8*)&Bs[p][0][wn + 16 + lm][cq];
        short8 b11 = *(const short8*)&Bs[p][1][wn + 16 + lm][cq];
        if (tt + 2 < nt) stB(pnn, (tt + 2) << 6);
        __builtin_amdgcn_sched_barrier(0);
        if (tt + 2 < nt) asm volatile("s_waitcnt vmcnt(6)" ::: "memory");
        else             asm volatile("s_waitcnt vmcnt(0)" ::: "memory");
        __builtin_amdgcn_s_barrier();
        asm volatile("s_waitcnt lgkmcnt(0)" ::: "memory");
        __builtin_amdgcn_sched_barrier(0);
        __builtin_amdgcn_s_setprio(1);
#pragma unroll
        for (int i = 0; i < 4; ++i) {
            acc[i][1] = MFMA16(a0[i], b10, acc[i][1]);
            acc[i][1] = MFMA16(a1[i], b11, acc[i][1]);
        }
        PHASE_END;
        p = pn;
    }

#pragma unroll
    for (int i = 0; i < 4; ++i)
#pragma unroll
        for (int j = 0; j < 2; ++j) {
            int col = bc + wn + j * 16 + lm;
            float bv = bias ? bias[col] : 0.f;
#pragma unroll
            for (int r = 0; r < 4; ++r) {
                int row = br + wm + i * 16 + quad * 4 + r;
                float v = acc[i][j][r] + bv;
                if (act == 1) v = 0.5f * v * (1.f + erff(v * 0.70710678118f));
                size_t idx = (size_t)row * N + col;
                if (resid) v += resid[idx];
                if (cF32) ((float*)C)[idx] = v;
                else ((unsigned short*)C)[idx] = f2bf(v);
            }
        }
}

// -------- GEMM 128xBN (R1-proven, fallback path) ----------------------------
template <int BN>
__global__ __launch_bounds__(256) void gemm_kernel(const unsigned short* __restrict__ A,
                                                   const unsigned short* __restrict__ BT,
                                                   const float* __restrict__ bias,
                                                   const float* __restrict__ resid,
                                                   void* __restrict__ C,
                                                   int M, int N, int K, int act, int cF32) {
    constexpr int NT = BN / 32;
    __shared__ __align__(16) unsigned short As[2][128][32];
    __shared__ __align__(16) unsigned short Bs[2][BN][32];
    int t = threadIdx.x, wave = t >> 6, lane = t & 63;
    int lm = lane & 15, quad = lane >> 4;
    int wm = (wave >> 1) * 64, wn = (wave & 1) * (BN / 2);

    int id = blockIdx.y * gridDim.x + blockIdx.x;
    int gsz = gridDim.x * 8;
    int grp = id / gsz, rem = id % gsz;
    int br = (grp * 8 + (rem & 7)) * 128;
    int bc = (rem >> 3) * BN;

    int srow = lane >> 2;
    int scol = ((lane & 3) ^ ((srow >> 1) & 3)) * 8;
    const unsigned short* Ag0 = A + (size_t)(br + wave * 32 + srow) * K + scol;
    const unsigned short* Ag1 = Ag0 + (size_t)16 * K;
    const unsigned short* Bg0 = BT + (size_t)(bc + wave * (BN / 4) + srow) * K + scol;
    const unsigned short* Bg1 = Bg0 + (size_t)16 * K;

    f32x4 zero4 = {0.f, 0.f, 0.f, 0.f};
    f32x4 acc[4][NT];
#pragma unroll
    for (int i = 0; i < 4; ++i)
#pragma unroll
        for (int j = 0; j < NT; ++j) acc[i][j] = zero4;

    auto stage = [&](int buf, int ko) {
        glds16(Ag0 + ko, &As[buf][wave * 32][0]);
        glds16(Ag1 + ko, &As[buf][wave * 32 + 16][0]);
        glds16(Bg0 + ko, &Bs[buf][wave * (BN / 4)][0]);
        if (BN == 128) glds16(Bg1 + ko, &Bs[buf][wave * (BN / 4) + 16][0]);
    };

    int nt = K >> 5;
    stage(0, 0);
    int rsw = (lm >> 1) & 3;
    int cq = (quad ^ rsw) << 3;
    for (int tt = 0; tt < nt; ++tt) {
        int cur = tt & 1;
        if (tt + 1 < nt) {
            stage(cur ^ 1, (tt + 1) << 5);
            if (BN == 128) asm volatile("s_waitcnt vmcnt(4)" ::: "memory");
            else           asm volatile("s_waitcnt vmcnt(3)" ::: "memory");
        } else {
            asm volatile("s_waitcnt vmcnt(0)" ::: "memory");
        }
        __builtin_amdgcn_s_barrier();
        __builtin_amdgcn_sched_barrier(0);
        short8 af[4], bf[NT];
#pragma unroll
        for (int i = 0; i < 4; ++i) af[i] = *(const short8*)&As[cur][wm + i * 16 + lm][cq];
#pragma unroll
        for (int j = 0; j < NT; ++j) bf[j] = *(const short8*)&Bs[cur][wn + j * 16 + lm][cq];
#pragma unroll
        for (int i = 0; i < 4; ++i)
#pragma unroll
            for (int j = 0; j < NT; ++j) acc[i][j] = MFMA16(af[i], bf[j], acc[i][j]);
        __builtin_amdgcn_sched_barrier(0);
        __builtin_amdgcn_s_barrier();
    }

#pragma unroll
    for (int i = 0; i < 4; ++i)
#pragma unroll
        for (int j = 0; j < NT; ++j) {
            int col = bc + wn + j * 16 + lm;
            float bv = bias ? bias[col] : 0.f;
#pragma unroll
            for (int r = 0; r < 4; ++r) {
                int row = br + wm + i * 16 + quad * 4 + r;
                float v = acc[i][j][r] + bv;
                if (act == 1) v = 0.5f * v * (1.f + erff(v * 0.70710678118f));
                size_t idx = (size_t)row * N + col;
                if (resid) v += resid[idx];
                if (cF32) ((float*)C)[idx] = v;
                else ((unsigned short*)C)[idx] = f2bf(v);
            }
        }
}

// -------- kvprep: repack K,V from qkv into glds16-ready swizzled layouts ----
__global__ __launch_bounds__(256) void kvprep_kernel(const unsigned short* __restrict__ qkv,
                                                     unsigned short* __restrict__ Kp,
                                                     unsigned short* __restrict__ Vt) {
    __shared__ unsigned short Vl[64][72];
    int t = threadIdx.x;
    int w = blockIdx.x, bh = blockIdx.y;
    int b = bh >> 4, h = bh & 15;
    int kt = w * 64;
    int sl = t >> 2, c = (t & 3) * 16;
    const unsigned short* src = qkv + (size_t)(b * 2048 + kt + sl) * 3072 + h * 64 + c;
    {
        uint4 k0 = *(const uint4*)(src + 1024);
        uint4 k1 = *(const uint4*)(src + 1024 + 8);
        int sw = sl & 7;
        int o0 = (c >> 3), o1 = o0 + 1;
        unsigned short* krow = Kp + ((size_t)bh * 2048 + kt + sl) * 64;
        *(uint4*)&krow[(o0 ^ sw) << 3] = k0;
        *(uint4*)&krow[(o1 ^ sw) << 3] = k1;
    }
    {
        uint4 v0 = *(const uint4*)(src + 2048);
        uint4 v1 = *(const uint4*)(src + 2048 + 8);
        *(uint4*)&Vl[sl][c] = v0;
        *(uint4*)&Vl[sl][c + 8] = v1;
    }
    __syncthreads();
    {
        int d = t >> 2, kc = (t & 3) * 16;
        unsigned short vv[16];
#pragma unroll
        for (int i = 0; i < 16; ++i) vv[i] = Vl[kc + i][d];
        int sw = d & 7;
        int ko0 = kc >> 3, ko1 = ko0 + 1;
        unsigned short* vrow = Vt + ((((size_t)bh * 32 + w) * 64) + d) * 64;
        *(uint4*)&vrow[(ko0 ^ sw) << 3] = *(uint4*)&vv[0];
        *(uint4*)&vrow[(ko1 ^ sw) << 3] = *(uint4*)&vv[8];
    }
}

// -------- attn2: glds16-staged K/V, fixed-shift softmax, T5 setprio ---------
__global__ __launch_bounds__(256) void attn2_kernel(const unsigned short* __restrict__ qkv,
                                                    const unsigned short* __restrict__ Kp,
                                                    const unsigned short* __restrict__ Vt,
                                                    unsigned short* __restrict__ out) {
    __shared__ __align__(16) unsigned short Qs[64][72];
    __shared__ __align__(16) unsigned short Ks[4096];
    __shared__ __align__(16) unsigned short Vs[4096];
    __shared__ __align__(16) unsigned short Ps[4][16][72];

    int t = threadIdx.x, wave = t >> 6, lane = t & 63;
    int lm = lane & 15, quad = lane >> 4, k8 = quad * 8;
    int bh = blockIdx.y, b = bh >> 4, h = bh & 15;
    int q0 = blockIdx.x * 64;
    const unsigned short* base = qkv + (size_t)b * 2048 * 3072 + h * 64;

    {
        int r = t >> 2, c = (t & 3) * 16;
        const unsigned short* src = base + (size_t)(q0 + r) * 3072 + c;
        *(uint4*)&Qs[r][c] = *(const uint4*)src;
        *(uint4*)&Qs[r][c + 8] = *(const uint4*)(src + 8);
    }
    __syncthreads();
    short8 qa0 = *(const short8*)&Qs[wave * 16 + lm][k8];
    short8 qa1 = *(const short8*)&Qs[wave * 16 + lm][32 + k8];

    f32x4 zero4 = {0.f, 0.f, 0.f, 0.f};
    f32x4 oacc[4] = {zero4, zero4, zero4, zero4};
    float lsum[4] = {0.f, 0.f, 0.f, 0.f};

    for (int kt = 0; kt < 2048; kt += 64) {
        __syncthreads();
        {
            const unsigned short* kg = Kp + ((size_t)bh * 2048 + kt) * 64 + wave * 1024 + (lane << 3);
            unsigned short* kl = &Ks[wave * 1024];
            glds16(kg, kl);
            glds16(kg + 512, kl + 512);
            const unsigned short* vg = Vt + (((size_t)bh * 32 + (kt >> 6)) * 64) * 64 + wave * 1024 + (lane << 3);
            unsigned short* vl = &Vs[wave * 1024];
            glds16(vg, vl);
            glds16(vg + 512, vl + 512);
        }
        __syncthreads();

        f32x4 s[4];
        __builtin_amdgcn_s_setprio(1);
#pragma unroll
        for (int nt = 0; nt < 4; ++nt) {
            int key = nt * 16 + lm;
            int swk = lm & 7;
            const unsigned short* krow = &Ks[key * 64];
            short8 kf0 = *(const short8*)&krow[(quad ^ swk) << 3];
            short8 kf1 = *(const short8*)&krow[((quad ^ swk) ^ 4) << 3];
            f32x4 a = zero4;
            a = MFMA16(qa0, kf0, a);
            a = MFMA16(qa1, kf1, a);
            s[nt] = a;
        }
        __builtin_amdgcn_s_setprio(0);

#pragma unroll
        for (int r = 0; r < 4; ++r) {
            int row = quad * 4 + r;
            int sw = (row >> 1) & 7;
#pragma unroll
            for (int nt = 0; nt < 4; ++nt) {
                float p = __expf(s[nt][r] * 0.125f - 8.0f);
                lsum[r] += p;
                int g = (nt << 1) + (lm >> 3);
                Ps[wave][row][((g ^ sw) << 3) + (lm & 7)] = f2bf(p);
            }
        }

        __builtin_amdgcn_s_setprio(1);
#pragma unroll
        for (int kh = 0; kh < 2; ++kh) {
            int pg = (kh << 2) + quad;
            short8 pa = *(const short8*)&Ps[wave][lm][(pg ^ ((lm >> 1) & 7)) << 3];
#pragma unroll
            for (int nt = 0; nt < 4; ++nt) {
                int d = nt * 16 + lm;
                short8 vf = *(const short8*)&Vs[d * 64 + ((pg ^ (lm & 7)) << 3)];
                oacc[nt] = MFMA16(pa, vf, oacc[nt]);
            }
        }
        __builtin_amdgcn_s_setprio(0);
    }

#pragma unroll
    for (int r = 0; r < 4; ++r) {
        float l = lsum[r];
        l += __shfl_xor(l, 1); l += __shfl_xor(l, 2);
        l += __shfl_xor(l, 4); l += __shfl_xor(l, 8);
        float inv = 1.f / l;
        int qrow = q0 + wave * 16 + quad * 4 + r;
        size_t o = ((size_t)(b * 2048 + qrow)) * 1024 + h * 64;
#pragma unroll
        for (int nt = 0; nt < 4; ++nt) out[o + nt * 16 + lm] = f2bf(oacc[nt][r] * inv);
    }
}

// -------- fallback attention (round-6 proven, interleaved qkv) --------------
__global__ __launch_bounds__(256) void attn_kernel(const unsigned short* __restrict__ qkv,
                                                   unsigned short* __restrict__ out) {
    __shared__ __align__(16) unsigned short Qs[64][72];
    __shared__ __align__(16) unsigned short Ks[64][72];
    __shared__ __align__(16) unsigned short Vs[64][72];
    __shared__ __align__(16) unsigned short Ps[4][16][72];
    int t = threadIdx.x, wave = t >> 6, lane = t & 63;
    int lm = lane & 15, quad = lane >> 4, k8 = quad * 8;
    int bh = blockIdx.y, b = bh >> 4, h = bh & 15;
    int q0 = blockIdx.x * 64;
    const unsigned short* base = qkv + (size_t)b * 2048 * 3072 + h * 64;
    const unsigned short* kb = base + 1024;
    const unsigned short* vb = base + 2048;
    {
        int r = t >> 2, c = (t & 3) * 16;
        const unsigned short* src = base + (size_t)(q0 + r) * 3072 + c;
        *(uint4*)&Qs[r][c] = *(const uint4*)src;
        *(uint4*)&Qs[r][c + 8] = *(const uint4*)(src + 8);
    }
    __syncthreads();
    short8 qa0 = *(const short8*)&Qs[wave * 16 + lm][k8];
    short8 qa1 = *(const short8*)&Qs[wave * 16 + lm][32 + k8];
    f32x4 zero4 = {0.f, 0.f, 0.f, 0.f};
    f32x4 oacc[4] = {zero4, zero4, zero4, zero4};
    float lsum[4] = {0.f, 0.f, 0.f, 0.f};
    int sr = t >> 2, sc = (t & 3) * 16;
    for (int kt = 0; kt < 2048; kt += 64) {
        __syncthreads();
        {
            const unsigned short* ksrc = kb + (size_t)(kt + sr) * 3072 + sc;
            *(uint4*)&Ks[sr][sc] = *(const uint4*)ksrc;
            *(uint4*)&Ks[sr][sc + 8] = *(const uint4*)(ksrc + 8);
            const unsigned short* vsrc = vb + (size_t)(kt + sr) * 3072 + sc;
            unsigned short tv[16] __attribute__((aligned(16)));
            *(uint4*)&tv[0] = *(const uint4*)vsrc;
            *(uint4*)&tv[8] = *(const uint4*)(vsrc + 8);
            int kg = sr >> 3, kw = sr & 7;
#pragma unroll
            for (int j = 0; j < 16; ++j) {
                int d = sc + j;
                Vs[d][((kg ^ ((d >> 3) & 7)) << 3) + kw] = tv[j];
            }
        }
        __syncthreads();
        f32x4 s[4];
#pragma unroll
        for (int nt = 0; nt < 4; ++nt) {
            short8 kf0 = *(const short8*)&Ks[nt * 16 + lm][k8];
            short8 kf1 = *(const short8*)&Ks[nt * 16 + lm][32 + k8];
            f32x4 a = zero4;
            a = MFMA16(qa0, kf0, a);
            a = MFMA16(qa1, kf1, a);
            s[nt] = a;
        }
#pragma unroll
        for (int r = 0; r < 4; ++r) {
            int row = quad * 4 + r;
            int sw = (row >> 1) & 7;
#pragma unroll
            for (int nt = 0; nt < 4; ++nt) {
                float p = __expf(s[nt][r] * 0.125f - 8.0f);
                lsum[r] += p;
                int g = (nt << 1) + (lm >> 3);
                Ps[wave][row][((g ^ sw) << 3) + (lm & 7)] = f2bf(p);
            }
        }
#pragma unroll
        for (int kh = 0; kh < 2; ++kh) {
            int pg = (kh << 2) + quad;
            short8 pa = *(const short8*)&Ps[wave][lm][(pg ^ ((lm >> 1) & 7)) << 3];
#pragma unroll
            for (int nt = 0; nt < 4; ++nt) {
                int d = nt * 16 + lm;
                short8 vf = *(const short8*)&Vs[d][(pg ^ ((d >> 3) & 7)) << 3];
                oacc[nt] = MFMA16(pa, vf, oacc[nt]);
            }
        }
    }
#pragma unroll
    for (int r = 0; r < 4; ++r) {
        float l = lsum[r];
        l += __shfl_xor(l, 1); l += __shfl_xor(l, 2);
        l += __shfl_xor(l, 4); l += __shfl_xor(l, 8);
        float inv = 1.f / l;
        int qrow = q0 + wave * 16 + quad * 4 + r;
        size_t o = ((size_t)(b * 2048 + qrow)) * 1024 + h * 64;
#pragma unroll
        for (int nt = 0; nt < 4; ++nt) out[o + nt * 16 + lm] = f2bf(oacc[nt][r] * inv);
    }
}

extern "C" void kernel_launch(void* const* d_in, const int* in_sizes, int n_in,
                              void* d_out, int out_size, void* d_ws, size_t ws_size,
                              hipStream_t stream) {
    const float* x      = (const float*)d_in[0];
    const float* w_qkv  = (const float*)d_in[1];
    const float* w_proj = (const float*)d_in[2];
    const float* b_proj = (const float*)d_in[3];
    const float* w_fc1  = (const float*)d_in[4];
    const float* b_fc1  = (const float*)d_in[5];
    const float* w_fc2  = (const float*)d_in[6];
    const float* b_fc2  = (const float*)d_in[7];
    const float* g1     = (const float*)d_in[8];
    const float* be1    = (const float*)d_in[9];
    const float* g2     = (const float*)d_in[10];
    const float* be2    = (const float*)d_in[11];
    float* out = (float*)d_out;
    unsigned short* sb = (unsigned short*)d_out;  // bf16 scratch in d_out [0,8 MiB)

    char* ws = (char*)d_ws;
    unsigned short* wqkvT  = (unsigned short*)ws;
    unsigned short* wprojT = (unsigned short*)(ws + ((size_t)6u << 20));
    unsigned short* wfc1T  = (unsigned short*)(ws + ((size_t)8u << 20));
    unsigned short* wfc2T  = (unsigned short*)(ws + ((size_t)16u << 20));
    unsigned short* qkv    = (unsigned short*)(ws + ((size_t)24u << 20));

    // 0. merged weight convert+transpose
    convt_all_kernel<<<dim3(12288), dim3(256), 0, stream>>>(
        w_qkv, w_proj, w_fc1, w_fc2, wqkvT, wprojT, wfc1T, wfc2T);
    // 1. h = LN1(x) -> d_out bf16
    ln_kernel<<<dim3(4096), dim3(256), 0, stream>>>(x, g1, be1, sb);
    // 2. qkv = h @ w_qkv  (256^2 4-phase)
    gemm256_kernel<<<dim3(12, 16), dim3(512), 0, stream>>>(
        sb, wqkvT, nullptr, nullptr, qkv, 4096, 3072, 1024, 0, 0);

    if (ws_size >= ((size_t)72u << 20)) {
        unsigned short* Kp = (unsigned short*)(ws + ((size_t)48u << 20));
        unsigned short* Vt = (unsigned short*)(ws + ((size_t)56u << 20));
        float*          x2 = (float*)(ws + ((size_t)24u << 20));
        unsigned short* m1 = (unsigned short*)(ws + ((size_t)40u << 20));
        // 3a. repack K,V into swizzled glds16-ready layouts
        kvprep_kernel<<<dim3(32, 32), dim3(256), 0, stream>>>(qkv, Kp, Vt);
        // 3b. attn -> d_out bf16 (h dead)
        attn2_kernel<<<dim3(32, 32), dim3(256), 0, stream>>>(qkv, Kp, Vt, sb);
        // 4. x2 = x + attn @ w_proj + b_proj  (128x64 ring-3 4-phase)
        gemm64_4ph<<<dim3(16, 32), dim3(256), 0, stream>>>(
            sb, wprojT, b_proj, x, x2, 4096, 1024, 1024, 0, 1);
        // 5. h2 = LN2(x2) -> d_out bf16
        ln_kernel<<<dim3(4096), dim3(256), 0, stream>>>(x2, g2, be2, sb);
        // 6. m1 = gelu(h2 @ w_fc1 + b_fc1)  (256^2 4-phase)
        gemm256_kernel<<<dim3(16, 16), dim3(512), 0, stream>>>(
            sb, wfc1T, b_fc1, nullptr, m1, 4096, 4096, 1024, 1, 0);
        // 7. out = x2 + m1 @ w_fc2 + b_fc2  (128x64 ring-3 4-phase, K=4096)
        gemm64_4ph<<<dim3(16, 32), dim3(256), 0, stream>>>(
            m1, wfc2T, b_fc2, x2, out, 4096, 1024, 4096, 0, 1);
    } else {
        float*          x2  = (float*)(ws + ((size_t)24u << 20));
        unsigned short* m1c = (unsigned short*)(ws + ((size_t)40u << 20));
        unsigned short* h2  = (unsigned short*)d_out + ((size_t)4u << 20);
        attn_kernel<<<dim3(32, 32), dim3(256), 0, stream>>>(qkv, sb);
        gemm_kernel<64><<<dim3(16, 32), dim3(256), 0, stream>>>(
            sb, wprojT, b_proj, x, x2, 4096, 1024, 1024, 0, 1);
        ln_kernel<<<dim3(4096), dim3(256), 0, stream>>>(x2, g2, be2, h2);
        for (int c = 0; c < 4; ++c) {
            size_t ro = (size_t)c * 1024;
            gemm_kernel<128><<<dim3(32, 8), dim3(256), 0, stream>>>(
                h2 + ro * 1024, wfc1T, b_fc1, nullptr, m1c, 1024, 4096, 1024, 1, 0);
            gemm_kernel<64><<<dim3(16, 8), dim3(256), 0, stream>>>(
                m1c, wfc2T, b_fc2, x2 + ro * 1024, out + ro * 1024, 1024, 1024, 4096, 0, 1);
        }
    }
}

// Round 6
// 370.741 us; speedup vs baseline: 1.2176x; 1.0690x over previous
//
#include <hip/hip_runtime.h>

typedef __attribute__((ext_vector_type(8))) short short8;
typedef __attribute__((ext_vector_type(4))) float f32x4;

#define MFMA16(a, b, c) __builtin_amdgcn_mfma_f32_16x16x32_bf16((a), (b), (c), 0, 0, 0)

static __device__ __forceinline__ unsigned short f2bf(float f) {
    unsigned int u = __float_as_uint(f);
    return (unsigned short)((u + 0x7fffu + ((u >> 16) & 1u)) >> 16);
}

// async 16B/lane global->LDS; LDS dest = wave-uniform base + lane*16
static __device__ __forceinline__ void glds16(const unsigned short* g, unsigned short* l) {
    __builtin_amdgcn_global_load_lds(
        (const __attribute__((address_space(1))) unsigned int*)g,
        (__attribute__((address_space(3))) unsigned int*)l, 16, 0, 0);
}

// -------- merged weight convert+transpose: W[K,N] fp32 -> WT[N,K] bf16 ------
__global__ __launch_bounds__(256) void convt_all_kernel(
    const float* __restrict__ w_qkv, const float* __restrict__ w_proj,
    const float* __restrict__ w_fc1, const float* __restrict__ w_fc2,
    unsigned short* __restrict__ wqkvT, unsigned short* __restrict__ wprojT,
    unsigned short* __restrict__ wfc1T, unsigned short* __restrict__ wfc2T) {
    __shared__ unsigned short Ts[32][33];
    int id = blockIdx.x;
    const float* W; unsigned short* WT; int K, N, bx, by;
    if (id < 3072)      { W = w_qkv;  WT = wqkvT;  K = 1024; N = 3072; bx = id % 96;  by = id / 96; }
    else if (id < 4096) { id -= 3072; W = w_proj; WT = wprojT; K = 1024; N = 1024; bx = id & 31; by = id >> 5; }
    else if (id < 8192) { id -= 4096; W = w_fc1;  WT = wfc1T;  K = 1024; N = 4096; bx = id & 127; by = id >> 7; }
    else                { id -= 8192; W = w_fc2;  WT = wfc2T;  K = 4096; N = 1024; bx = id & 31; by = id >> 5; }
    int t = threadIdx.x;
    int bk = by * 32, bn = bx * 32;
    int r = t >> 3, c = (t & 7) * 4;
    float4 w = *(const float4*)&W[(size_t)(bk + r) * N + bn + c];
    Ts[c + 0][r] = f2bf(w.x); Ts[c + 1][r] = f2bf(w.y);
    Ts[c + 2][r] = f2bf(w.z); Ts[c + 3][r] = f2bf(w.w);
    __syncthreads();
    ushort4 o;
    o.x = Ts[r][c]; o.y = Ts[r][c + 1]; o.z = Ts[r][c + 2]; o.w = Ts[r][c + 3];
    *(ushort4*)&WT[(size_t)(bn + r) * K + bk + c] = o;
}

// ---------------- LayerNorm: fp32 in -> bf16 out ----------------------------
__global__ __launch_bounds__(256) void ln_kernel(const float* __restrict__ x,
                                                 const float* __restrict__ g,
                                                 const float* __restrict__ be,
                                                 unsigned short* __restrict__ y) {
    int row = blockIdx.x;
    const float* xr = x + (size_t)row * 1024;
    unsigned short* yr = y + (size_t)row * 1024;
    int t = threadIdx.x;
    float v[4];
    float sum = 0.f, sq = 0.f;
#pragma unroll
    for (int i = 0; i < 4; ++i) {
        float f = xr[t + i * 256];
        v[i] = f; sum += f; sq += f * f;
    }
#pragma unroll
    for (int o = 32; o > 0; o >>= 1) { sum += __shfl_down(sum, o); sq += __shfl_down(sq, o); }
    __shared__ float red[8];
    int wave = t >> 6, lane = t & 63;
    if (lane == 0) { red[wave] = sum; red[4 + wave] = sq; }
    __syncthreads();
    sum = red[0] + red[1] + red[2] + red[3];
    sq  = red[4] + red[5] + red[6] + red[7];
    float mean = sum * (1.f / 1024.f);
    float var  = sq * (1.f / 1024.f) - mean * mean;
    float rstd = rsqrtf(var + 1e-5f);
#pragma unroll
    for (int i = 0; i < 4; ++i) {
        int c = t + i * 256;
        yr[c] = f2bf((v[i] - mean) * rstd * g[c] + be[c]);
    }
}

// phase sync macros (R4/R5-proven)
#define PHASE_MID                                            \
    __builtin_amdgcn_sched_barrier(0);                       \
    __builtin_amdgcn_s_barrier();                            \
    asm volatile("s_waitcnt lgkmcnt(0)" ::: "memory");       \
    __builtin_amdgcn_sched_barrier(0);                       \
    __builtin_amdgcn_s_setprio(1);
#define PHASE_END                                            \
    __builtin_amdgcn_s_setprio(0);                           \
    __builtin_amdgcn_sched_barrier(0);                       \
    __builtin_amdgcn_s_barrier();

// -------- GEMM 128x256, BK=32, ring-3, 2 blocks/CU --------------------------
// R5 post-mortem: gemm256's 128KB LDS pinned 1 block/CU; phase LDS bursts
// (96 ds_read) serialized against MFMA bursts with nothing to fill stalls
// (Occupancy 20.6, MfmaUtil 17.6). This kernel trades tile depth for
// occupancy: LDS = 3 ring bufs x (A 8KB + B 16KB) = 72KB -> 2 blocks/CU;
// __launch_bounds__(512,4) forces VGPR<=128 so 16 waves/CU fit. 8 waves
// (2M x 4N), wave-tile 64x64 (acc[4][4]); one phase per K-tile (BK=32):
// {8 ds_read; stage tile t+2 (3 glds16); vmcnt(3); bar; lgkm0; setprio;
// 16 MFMA; setprio0; bar}. vmcnt(3) = loads-per-tile leaves only the
// just-staged t+2 outstanding => tile t+1 confirmed arrived (same proven
// invariant as gemm64_4ph; 2-iter flight covers HBM latency; barrier
// makes the per-wave vmcnt a cross-wave guarantee). Both-sides XOR swizzle
// (R1-verified, conflicts==0). Requires M%128==0, N%256==0, gridDim.y%8==0,
// K%32==0, K>=96.
__global__ __launch_bounds__(512, 4) void gemm128x256_kernel(
    const unsigned short* __restrict__ A, const unsigned short* __restrict__ BT,
    const float* __restrict__ bias, const float* __restrict__ resid,
    void* __restrict__ C, int M, int N, int K, int act, int cF32) {
    __shared__ __align__(16) unsigned short As[3][128][32];
    __shared__ __align__(16) unsigned short Bs[3][256][32];
    int t = threadIdx.x, wave = t >> 6, lane = t & 63;
    int lm = lane & 15, quad = lane >> 4;
    int wm = (wave >> 2) * 64, wn = (wave & 3) * 64;

    int id = blockIdx.y * gridDim.x + blockIdx.x;
    int gsz = gridDim.x * 8;
    int grp = id / gsz, rem = id % gsz;
    int br = (grp * 8 + (rem & 7)) * 128;
    int bc = (rem >> 3) * 256;

    int srow = lane >> 2;
    int scol = ((lane & 3) ^ ((srow >> 1) & 3)) * 8;
    const unsigned short* Ag = A + (size_t)(br + wave * 16 + srow) * K + scol;
    const unsigned short* Bg = BT + (size_t)(bc + wave * 32 + srow) * K + scol;

    // one K-tile stage = 3 glds16/wave: A 128x32 (1), B 256x32 (2)
    auto stage = [&](int b, int ko) {
        glds16(Ag + ko, &As[b][wave * 16][0]);
        glds16(Bg + ko, &Bs[b][wave * 32][0]);
        glds16(Bg + (size_t)16 * K + ko, &Bs[b][wave * 32 + 16][0]);
    };

    f32x4 zero4 = {0.f, 0.f, 0.f, 0.f};
    f32x4 acc[4][4];
#pragma unroll
    for (int i = 0; i < 4; ++i)
#pragma unroll
        for (int j = 0; j < 4; ++j) acc[i][j] = zero4;

    int nt = K >> 5;
    stage(0, 0);
    stage(1, 32);
    __builtin_amdgcn_sched_barrier(0);
    asm volatile("s_waitcnt vmcnt(3)" ::: "memory");  // tile0 confirmed
    __builtin_amdgcn_s_barrier();

    int cq = (quad ^ ((lm >> 1) & 3)) << 3;  // swizzled column (shorts)

    int p = 0;
    for (int tt = 0; tt < nt; ++tt) {
        int pnn = p + 2; if (pnn >= 3) pnn -= 3;
        short8 af[4], bf[4];
#pragma unroll
        for (int i = 0; i < 4; ++i) af[i] = *(const short8*)&As[p][wm + i * 16 + lm][cq];
#pragma unroll
        for (int j = 0; j < 4; ++j) bf[j] = *(const short8*)&Bs[p][wn + j * 16 + lm][cq];
        if (tt + 2 < nt) {
            stage(pnn, (tt + 2) << 5);
            __builtin_amdgcn_sched_barrier(0);
            asm volatile("s_waitcnt vmcnt(3)" ::: "memory");  // t+1 confirmed
        } else {
            __builtin_amdgcn_sched_barrier(0);
            asm volatile("s_waitcnt vmcnt(0)" ::: "memory");
        }
        __builtin_amdgcn_s_barrier();
        asm volatile("s_waitcnt lgkmcnt(0)" ::: "memory");
        __builtin_amdgcn_sched_barrier(0);
        __builtin_amdgcn_s_setprio(1);
#pragma unroll
        for (int i = 0; i < 4; ++i)
#pragma unroll
            for (int j = 0; j < 4; ++j) acc[i][j] = MFMA16(af[i], bf[j], acc[i][j]);
        PHASE_END;
        p = p + 1; if (p == 3) p = 0;
    }

#pragma unroll
    for (int i = 0; i < 4; ++i)
#pragma unroll
        for (int j = 0; j < 4; ++j) {
            int col = bc + wn + j * 16 + lm;
            float bv = bias ? bias[col] : 0.f;
#pragma unroll
            for (int r = 0; r < 4; ++r) {
                int row = br + wm + i * 16 + quad * 4 + r;
                float v = acc[i][j][r] + bv;
                if (act == 1) v = 0.5f * v * (1.f + erff(v * 0.70710678118f));
                size_t idx = (size_t)row * N + col;
                if (resid) v += resid[idx];
                if (cF32) ((float*)C)[idx] = v;
                else ((unsigned short*)C)[idx] = f2bf(v);
            }
        }
}

// -------- GEMM 128x64, 2-phase/K-tile, ring-3, stage-2-ahead (R5-proven) ----
__global__ __launch_bounds__(256) void gemm64_4ph(const unsigned short* __restrict__ A,
                                                  const unsigned short* __restrict__ BT,
                                                  const float* __restrict__ bias,
                                                  const float* __restrict__ resid,
                                                  void* __restrict__ C,
                                                  int M, int N, int K, int act, int cF32) {
    __shared__ __align__(16) unsigned short As[3][2][128][32];
    __shared__ __align__(16) unsigned short Bs[3][2][64][32];
    int t = threadIdx.x, wave = t >> 6, lane = t & 63;
    int lm = lane & 15, quad = lane >> 4;
    int wm = (wave >> 1) * 64, wn = (wave & 1) * 32;

    int id = blockIdx.y * gridDim.x + blockIdx.x;
    int gsz = gridDim.x * 8;
    int grp = id / gsz, rem = id % gsz;
    int br = (grp * 8 + (rem & 7)) * 128;
    int bc = (rem >> 3) * 64;

    int srow = lane >> 2;
    int scol = ((lane & 3) ^ ((srow >> 1) & 3)) * 8;
    const unsigned short* Ag = A + (size_t)(br + wave * 16 + srow) * K + scol;
    const unsigned short* Bg = BT + (size_t)(bc + wave * 16 + srow) * K + scol;

    auto stA = [&](int b, int ko) {
#pragma unroll
        for (int l = 0; l < 4; ++l)
            glds16(Ag + (size_t)(l >> 1) * 64 * K + (l & 1) * 32 + ko,
                   &As[b][l & 1][(l >> 1) * 64 + wave * 16][0]);
    };
    auto stB = [&](int b, int ko) {
#pragma unroll
        for (int l = 0; l < 2; ++l)
            glds16(Bg + (size_t)l * 32 + ko, &Bs[b][l][wave * 16][0]);
    };

    f32x4 zero4 = {0.f, 0.f, 0.f, 0.f};
    f32x4 acc[4][2];
#pragma unroll
    for (int i = 0; i < 4; ++i) { acc[i][0] = zero4; acc[i][1] = zero4; }

    int nt = K >> 6;
    stA(0, 0); stB(0, 0);
    if (nt > 1) { stA(1, 64); stB(1, 64); }
    __builtin_amdgcn_sched_barrier(0);
    if (nt > 1) asm volatile("s_waitcnt vmcnt(6)" ::: "memory");
    else        asm volatile("s_waitcnt vmcnt(0)" ::: "memory");
    __builtin_amdgcn_s_barrier();

    int cq = (quad ^ ((lm >> 1) & 3)) << 3;

    int p = 0;
    for (int tt = 0; tt < nt; ++tt) {
        int pn = p + 1; if (pn == 3) pn = 0;
        int pnn = pn + 1; if (pnn == 3) pnn = 0;
        // ---- P1 ----
        short8 a0[4], a1[4], b00, b01;
#pragma unroll
        for (int i = 0; i < 4; ++i) {
            a0[i] = *(const short8*)&As[p][0][wm + i * 16 + lm][cq];
            a1[i] = *(const short8*)&As[p][1][wm + i * 16 + lm][cq];
        }
        b00 = *(const short8*)&Bs[p][0][wn + lm][cq];
        b01 = *(const short8*)&Bs[p][1][wn + lm][cq];
        if (tt + 2 < nt) stA(pnn, (tt + 2) << 6);
        PHASE_MID;
#pragma unroll
        for (int i = 0; i < 4; ++i) {
            acc[i][0] = MFMA16(a0[i], b00, acc[i][0]);
            acc[i][0] = MFMA16(a1[i], b01, acc[i][0]);
        }
        PHASE_END;
        // ---- P2 ----
        short8 b10 = *(const short8*)&Bs[p][0][wn + 16 + lm][cq];
        short8 b11 = *(const short8*)&Bs[p][1][wn + 16 + lm][cq];
        if (tt + 2 < nt) stB(pnn, (tt + 2) << 6);
        __builtin_amdgcn_sched_barrier(0);
        if (tt + 2 < nt) asm volatile("s_waitcnt vmcnt(6)" ::: "memory");
        else             asm volatile("s_waitcnt vmcnt(0)" ::: "memory");
        __builtin_amdgcn_s_barrier();
        asm volatile("s_waitcnt lgkmcnt(0)" ::: "memory");
        __builtin_amdgcn_sched_barrier(0);
        __builtin_amdgcn_s_setprio(1);
#pragma unroll
        for (int i = 0; i < 4; ++i) {
            acc[i][1] = MFMA16(a0[i], b10, acc[i][1]);
            acc[i][1] = MFMA16(a1[i], b11, acc[i][1]);
        }
        PHASE_END;
        p = pn;
    }

#pragma unroll
    for (int i = 0; i < 4; ++i)
#pragma unroll
        for (int j = 0; j < 2; ++j) {
            int col = bc + wn + j * 16 + lm;
            float bv = bias ? bias[col] : 0.f;
#pragma unroll
            for (int r = 0; r < 4; ++r) {
                int row = br + wm + i * 16 + quad * 4 + r;
                float v = acc[i][j][r] + bv;
                if (act == 1) v = 0.5f * v * (1.f + erff(v * 0.70710678118f));
                size_t idx = (size_t)row * N + col;
                if (resid) v += resid[idx];
                if (cF32) ((float*)C)[idx] = v;
                else ((unsigned short*)C)[idx] = f2bf(v);
            }
        }
}

// -------- GEMM 128xBN (R1-proven, fallback path) ----------------------------
template <int BN>
__global__ __launch_bounds__(256) void gemm_kernel(const unsigned short* __restrict__ A,
                                                   const unsigned short* __restrict__ BT,
                                                   const float* __restrict__ bias,
                                                   const float* __restrict__ resid,
                                                   void* __restrict__ C,
                                                   int M, int N, int K, int act, int cF32) {
    constexpr int NT = BN / 32;
    __shared__ __align__(16) unsigned short As[2][128][32];
    __shared__ __align__(16) unsigned short Bs[2][BN][32];
    int t = threadIdx.x, wave = t >> 6, lane = t & 63;
    int lm = lane & 15, quad = lane >> 4;
    int wm = (wave >> 1) * 64, wn = (wave & 1) * (BN / 2);

    int id = blockIdx.y * gridDim.x + blockIdx.x;
    int gsz = gridDim.x * 8;
    int grp = id / gsz, rem = id % gsz;
    int br = (grp * 8 + (rem & 7)) * 128;
    int bc = (rem >> 3) * BN;

    int srow = lane >> 2;
    int scol = ((lane & 3) ^ ((srow >> 1) & 3)) * 8;
    const unsigned short* Ag0 = A + (size_t)(br + wave * 32 + srow) * K + scol;
    const unsigned short* Ag1 = Ag0 + (size_t)16 * K;
    const unsigned short* Bg0 = BT + (size_t)(bc + wave * (BN / 4) + srow) * K + scol;
    const unsigned short* Bg1 = Bg0 + (size_t)16 * K;

    f32x4 zero4 = {0.f, 0.f, 0.f, 0.f};
    f32x4 acc[4][NT];
#pragma unroll
    for (int i = 0; i < 4; ++i)
#pragma unroll
        for (int j = 0; j < NT; ++j) acc[i][j] = zero4;

    auto stage = [&](int buf, int ko) {
        glds16(Ag0 + ko, &As[buf][wave * 32][0]);
        glds16(Ag1 + ko, &As[buf][wave * 32 + 16][0]);
        glds16(Bg0 + ko, &Bs[buf][wave * (BN / 4)][0]);
        if (BN == 128) glds16(Bg1 + ko, &Bs[buf][wave * (BN / 4) + 16][0]);
    };

    int nt = K >> 5;
    stage(0, 0);
    int rsw = (lm >> 1) & 3;
    int cq = (quad ^ rsw) << 3;
    for (int tt = 0; tt < nt; ++tt) {
        int cur = tt & 1;
        if (tt + 1 < nt) {
            stage(cur ^ 1, (tt + 1) << 5);
            if (BN == 128) asm volatile("s_waitcnt vmcnt(4)" ::: "memory");
            else           asm volatile("s_waitcnt vmcnt(3)" ::: "memory");
        } else {
            asm volatile("s_waitcnt vmcnt(0)" ::: "memory");
        }
        __builtin_amdgcn_s_barrier();
        __builtin_amdgcn_sched_barrier(0);
        short8 af[4], bf[NT];
#pragma unroll
        for (int i = 0; i < 4; ++i) af[i] = *(const short8*)&As[cur][wm + i * 16 + lm][cq];
#pragma unroll
        for (int j = 0; j < NT; ++j) bf[j] = *(const short8*)&Bs[cur][wn + j * 16 + lm][cq];
#pragma unroll
        for (int i = 0; i < 4; ++i)
#pragma unroll
            for (int j = 0; j < NT; ++j) acc[i][j] = MFMA16(af[i], bf[j], acc[i][j]);
        __builtin_amdgcn_sched_barrier(0);
        __builtin_amdgcn_s_barrier();
    }

#pragma unroll
    for (int i = 0; i < 4; ++i)
#pragma unroll
        for (int j = 0; j < NT; ++j) {
            int col = bc + wn + j * 16 + lm;
            float bv = bias ? bias[col] : 0.f;
#pragma unroll
            for (int r = 0; r < 4; ++r) {
                int row = br + wm + i * 16 + quad * 4 + r;
                float v = acc[i][j][r] + bv;
                if (act == 1) v = 0.5f * v * (1.f + erff(v * 0.70710678118f));
                size_t idx = (size_t)row * N + col;
                if (resid) v += resid[idx];
                if (cF32) ((float*)C)[idx] = v;
                else ((unsigned short*)C)[idx] = f2bf(v);
            }
        }
}

// -------- kvprep: repack K,V from qkv into glds16-ready swizzled layouts ----
__global__ __launch_bounds__(256) void kvprep_kernel(const unsigned short* __restrict__ qkv,
                                                     unsigned short* __restrict__ Kp,
                                                     unsigned short* __restrict__ Vt) {
    __shared__ unsigned short Vl[64][72];
    int t = threadIdx.x;
    int w = blockIdx.x, bh = blockIdx.y;
    int b = bh >> 4, h = bh & 15;
    int kt = w * 64;
    int sl = t >> 2, c = (t & 3) * 16;
    const unsigned short* src = qkv + (size_t)(b * 2048 + kt + sl) * 3072 + h * 64 + c;
    {
        uint4 k0 = *(const uint4*)(src + 1024);
        uint4 k1 = *(const uint4*)(src + 1024 + 8);
        int sw = sl & 7;
        int o0 = (c >> 3), o1 = o0 + 1;
        unsigned short* krow = Kp + ((size_t)bh * 2048 + kt + sl) * 64;
        *(uint4*)&krow[(o0 ^ sw) << 3] = k0;
        *(uint4*)&krow[(o1 ^ sw) << 3] = k1;
    }
    {
        uint4 v0 = *(const uint4*)(src + 2048);
        uint4 v1 = *(const uint4*)(src + 2048 + 8);
        *(uint4*)&Vl[sl][c] = v0;
        *(uint4*)&Vl[sl][c + 8] = v1;
    }
    __syncthreads();
    {
        int d = t >> 2, kc = (t & 3) * 16;
        unsigned short vv[16];
#pragma unroll
        for (int i = 0; i < 16; ++i) vv[i] = Vl[kc + i][d];
        int sw = d & 7;
        int ko0 = kc >> 3, ko1 = ko0 + 1;
        unsigned short* vrow = Vt + ((((size_t)bh * 32 + w) * 64) + d) * 64;
        *(uint4*)&vrow[(ko0 ^ sw) << 3] = *(uint4*)&vv[0];
        *(uint4*)&vrow[(ko1 ^ sw) << 3] = *(uint4*)&vv[8];
    }
}

// -------- attn2: glds16-staged K/V, fixed-shift softmax, T5 setprio ---------
__global__ __launch_bounds__(256) void attn2_kernel(const unsigned short* __restrict__ qkv,
                                                    const unsigned short* __restrict__ Kp,
                                                    const unsigned short* __restrict__ Vt,
                                                    unsigned short* __restrict__ out) {
    __shared__ __align__(16) unsigned short Qs[64][72];
    __shared__ __align__(16) unsigned short Ks[4096];
    __shared__ __align__(16) unsigned short Vs[4096];
    __shared__ __align__(16) unsigned short Ps[4][16][72];

    int t = threadIdx.x, wave = t >> 6, lane = t & 63;
    int lm = lane & 15, quad = lane >> 4, k8 = quad * 8;
    int bh = blockIdx.y, b = bh >> 4, h = bh & 15;
    int q0 = blockIdx.x * 64;
    const unsigned short* base = qkv + (size_t)b * 2048 * 3072 + h * 64;

    {
        int r = t >> 2, c = (t & 3) * 16;
        const unsigned short* src = base + (size_t)(q0 + r) * 3072 + c;
        *(uint4*)&Qs[r][c] = *(const uint4*)src;
        *(uint4*)&Qs[r][c + 8] = *(const uint4*)(src + 8);
    }
    __syncthreads();
    short8 qa0 = *(const short8*)&Qs[wave * 16 + lm][k8];
    short8 qa1 = *(const short8*)&Qs[wave * 16 + lm][32 + k8];

    f32x4 zero4 = {0.f, 0.f, 0.f, 0.f};
    f32x4 oacc[4] = {zero4, zero4, zero4, zero4};
    float lsum[4] = {0.f, 0.f, 0.f, 0.f};

    for (int kt = 0; kt < 2048; kt += 64) {
        __syncthreads();
        {
            const unsigned short* kg = Kp + ((size_t)bh * 2048 + kt) * 64 + wave * 1024 + (lane << 3);
            unsigned short* kl = &Ks[wave * 1024];
            glds16(kg, kl);
            glds16(kg + 512, kl + 512);
            const unsigned short* vg = Vt + (((size_t)bh * 32 + (kt >> 6)) * 64) * 64 + wave * 1024 + (lane << 3);
            unsigned short* vl = &Vs[wave * 1024];
            glds16(vg, vl);
            glds16(vg + 512, vl + 512);
        }
        __syncthreads();

        f32x4 s[4];
        __builtin_amdgcn_s_setprio(1);
#pragma unroll
        for (int nt = 0; nt < 4; ++nt) {
            int key = nt * 16 + lm;
            int swk = lm & 7;
            const unsigned short* krow = &Ks[key * 64];
            short8 kf0 = *(const short8*)&krow[(quad ^ swk) << 3];
            short8 kf1 = *(const short8*)&krow[((quad ^ swk) ^ 4) << 3];
            f32x4 a = zero4;
            a = MFMA16(qa0, kf0, a);
            a = MFMA16(qa1, kf1, a);
            s[nt] = a;
        }
        __builtin_amdgcn_s_setprio(0);

#pragma unroll
        for (int r = 0; r < 4; ++r) {
            int row = quad * 4 + r;
            int sw = (row >> 1) & 7;
#pragma unroll
            for (int nt = 0; nt < 4; ++nt) {
                float p = __expf(s[nt][r] * 0.125f - 8.0f);
                lsum[r] += p;
                int g = (nt << 1) + (lm >> 3);
                Ps[wave][row][((g ^ sw) << 3) + (lm & 7)] = f2bf(p);
            }
        }

        __builtin_amdgcn_s_setprio(1);
#pragma unroll
        for (int kh = 0; kh < 2; ++kh) {
            int pg = (kh << 2) + quad;
            short8 pa = *(const short8*)&Ps[wave][lm][(pg ^ ((lm >> 1) & 7)) << 3];
#pragma unroll
            for (int nt = 0; nt < 4; ++nt) {
                int d = nt * 16 + lm;
                short8 vf = *(const short8*)&Vs[d * 64 + ((pg ^ (lm & 7)) << 3)];
                oacc[nt] = MFMA16(pa, vf, oacc[nt]);
            }
        }
        __builtin_amdgcn_s_setprio(0);
    }

#pragma unroll
    for (int r = 0; r < 4; ++r) {
        float l = lsum[r];
        l += __shfl_xor(l, 1); l += __shfl_xor(l, 2);
        l += __shfl_xor(l, 4); l += __shfl_xor(l, 8);
        float inv = 1.f / l;
        int qrow = q0 + wave * 16 + quad * 4 + r;
        size_t o = ((size_t)(b * 2048 + qrow)) * 1024 + h * 64;
#pragma unroll
        for (int nt = 0; nt < 4; ++nt) out[o + nt * 16 + lm] = f2bf(oacc[nt][r] * inv);
    }
}

// -------- fallback attention (round-6 proven, interleaved qkv) --------------
__global__ __launch_bounds__(256) void attn_kernel(const unsigned short* __restrict__ qkv,
                                                   unsigned short* __restrict__ out) {
    __shared__ __align__(16) unsigned short Qs[64][72];
    __shared__ __align__(16) unsigned short Ks[64][72];
    __shared__ __align__(16) unsigned short Vs[64][72];
    __shared__ __align__(16) unsigned short Ps[4][16][72];
    int t = threadIdx.x, wave = t >> 6, lane = t & 63;
    int lm = lane & 15, quad = lane >> 4, k8 = quad * 8;
    int bh = blockIdx.y, b = bh >> 4, h = bh & 15;
    int q0 = blockIdx.x * 64;
    const unsigned short* base = qkv + (size_t)b * 2048 * 3072 + h * 64;
    const unsigned short* kb = base + 1024;
    const unsigned short* vb = base + 2048;
    {
        int r = t >> 2, c = (t & 3) * 16;
        const unsigned short* src = base + (size_t)(q0 + r) * 3072 + c;
        *(uint4*)&Qs[r][c] = *(const uint4*)src;
        *(uint4*)&Qs[r][c + 8] = *(const uint4*)(src + 8);
    }
    __syncthreads();
    short8 qa0 = *(const short8*)&Qs[wave * 16 + lm][k8];
    short8 qa1 = *(const short8*)&Qs[wave * 16 + lm][32 + k8];
    f32x4 zero4 = {0.f, 0.f, 0.f, 0.f};
    f32x4 oacc[4] = {zero4, zero4, zero4, zero4};
    float lsum[4] = {0.f, 0.f, 0.f, 0.f};
    int sr = t >> 2, sc = (t & 3) * 16;
    for (int kt = 0; kt < 2048; kt += 64) {
        __syncthreads();
        {
            const unsigned short* ksrc = kb + (size_t)(kt + sr) * 3072 + sc;
            *(uint4*)&Ks[sr][sc] = *(const uint4*)ksrc;
            *(uint4*)&Ks[sr][sc + 8] = *(const uint4*)(ksrc + 8);
            const unsigned short* vsrc = vb + (size_t)(kt + sr) * 3072 + sc;
            unsigned short tv[16] __attribute__((aligned(16)));
            *(uint4*)&tv[0] = *(const uint4*)vsrc;
            *(uint4*)&tv[8] = *(const uint4*)(vsrc + 8);
            int kg = sr >> 3, kw = sr & 7;
#pragma unroll
            for (int j = 0; j < 16; ++j) {
                int d = sc + j;
                Vs[d][((kg ^ ((d >> 3) & 7)) << 3) + kw] = tv[j];
            }
        }
        __syncthreads();
        f32x4 s[4];
#pragma unroll
        for (int nt = 0; nt < 4; ++nt) {
            short8 kf0 = *(const short8*)&Ks[nt * 16 + lm][k8];
            short8 kf1 = *(const short8*)&Ks[nt * 16 + lm][32 + k8];
            f32x4 a = zero4;
            a = MFMA16(qa0, kf0, a);
            a = MFMA16(qa1, kf1, a);
            s[nt] = a;
        }
#pragma unroll
        for (int r = 0; r < 4; ++r) {
            int row = quad * 4 + r;
            int sw = (row >> 1) & 7;
#pragma unroll
            for (int nt = 0; nt < 4; ++nt) {
                float p = __expf(s[nt][r] * 0.125f - 8.0f);
                lsum[r] += p;
                int g = (nt << 1) + (lm >> 3);
                Ps[wave][row][((g ^ sw) << 3) + (lm & 7)] = f2bf(p);
            }
        }
#pragma unroll
        for (int kh = 0; kh < 2; ++kh) {
            int pg = (kh << 2) + quad;
            short8 pa = *(const short8*)&Ps[wave][lm][(pg ^ ((lm >> 1) & 7)) << 3];
#pragma unroll
            for (int nt = 0; nt < 4; ++nt) {
                int d = nt * 16 + lm;
                short8 vf = *(const short8*)&Vs[d][(pg ^ ((d >> 3) & 7)) << 3];
                oacc[nt] = MFMA16(pa, vf, oacc[nt]);
            }
        }
    }
#pragma unroll
    for (int r = 0; r < 4; ++r) {
        float l = lsum[r];
        l += __shfl_xor(l, 1); l += __shfl_xor(l, 2);
        l += __shfl_xor(l, 4); l += __shfl_xor(l, 8);
        float inv = 1.f / l;
        int qrow = q0 + wave * 16 + quad * 4 + r;
        size_t o = ((size_t)(b * 2048 + qrow)) * 1024 + h * 64;
#pragma unroll
        for (int nt = 0; nt < 4; ++nt) out[o + nt * 16 + lm] = f2bf(oacc[nt][r] * inv);
    }
}

extern "C" void kernel_launch(void* const* d_in, const int* in_sizes, int n_in,
                              void* d_out, int out_size, void* d_ws, size_t ws_size,
                              hipStream_t stream) {
    const float* x      = (const float*)d_in[0];
    const float* w_qkv  = (const float*)d_in[1];
    const float* w_proj = (const float*)d_in[2];
    const float* b_proj = (const float*)d_in[3];
    const float* w_fc1  = (const float*)d_in[4];
    const float* b_fc1  = (const float*)d_in[5];
    const float* w_fc2  = (const float*)d_in[6];
    const float* b_fc2  = (const float*)d_in[7];
    const float* g1     = (const float*)d_in[8];
    const float* be1    = (const float*)d_in[9];
    const float* g2     = (const float*)d_in[10];
    const float* be2    = (const float*)d_in[11];
    float* out = (float*)d_out;
    unsigned short* sb = (unsigned short*)d_out;  // bf16 scratch in d_out [0,8 MiB)

    char* ws = (char*)d_ws;
    unsigned short* wqkvT  = (unsigned short*)ws;
    unsigned short* wprojT = (unsigned short*)(ws + ((size_t)6u << 20));
    unsigned short* wfc1T  = (unsigned short*)(ws + ((size_t)8u << 20));
    unsigned short* wfc2T  = (unsigned short*)(ws + ((size_t)16u << 20));
    unsigned short* qkv    = (unsigned short*)(ws + ((size_t)24u << 20));

    // 0. merged weight convert+transpose
    convt_all_kernel<<<dim3(12288), dim3(256), 0, stream>>>(
        w_qkv, w_proj, w_fc1, w_fc2, wqkvT, wprojT, wfc1T, wfc2T);
    // 1. h = LN1(x) -> d_out bf16
    ln_kernel<<<dim3(4096), dim3(256), 0, stream>>>(x, g1, be1, sb);
    // 2. qkv = h @ w_qkv  (128x256 ring-3, 384 blocks = 1.5/CU)
    gemm128x256_kernel<<<dim3(12, 32), dim3(512), 0, stream>>>(
        sb, wqkvT, nullptr, nullptr, qkv, 4096, 3072, 1024, 0, 0);

    if (ws_size >= ((size_t)72u << 20)) {
        unsigned short* Kp = (unsigned short*)(ws + ((size_t)48u << 20));
        unsigned short* Vt = (unsigned short*)(ws + ((size_t)56u << 20));
        float*          x2 = (float*)(ws + ((size_t)24u << 20));
        unsigned short* m1 = (unsigned short*)(ws + ((size_t)40u << 20));
        // 3a. repack K,V into swizzled glds16-ready layouts
        kvprep_kernel<<<dim3(32, 32), dim3(256), 0, stream>>>(qkv, Kp, Vt);
        // 3b. attn -> d_out bf16 (h dead)
        attn2_kernel<<<dim3(32, 32), dim3(256), 0, stream>>>(qkv, Kp, Vt, sb);
        // 4. x2 = x + attn @ w_proj + b_proj  (128x64 ring-3 4-phase)
        gemm64_4ph<<<dim3(16, 32), dim3(256), 0, stream>>>(
            sb, wprojT, b_proj, x, x2, 4096, 1024, 1024, 0, 1);
        // 5. h2 = LN2(x2) -> d_out bf16
        ln_kernel<<<dim3(4096), dim3(256), 0, stream>>>(x2, g2, be2, sb);
        // 6. m1 = gelu(h2 @ w_fc1 + b_fc1)  (128x256 ring-3, 512 blocks = 2/CU)
        gemm128x256_kernel<<<dim3(16, 32), dim3(512), 0, stream>>>(
            sb, wfc1T, b_fc1, nullptr, m1, 4096, 4096, 1024, 1, 0);
        // 7. out = x2 + m1 @ w_fc2 + b_fc2  (128x64 ring-3 4-phase, K=4096)
        gemm64_4ph<<<dim3(16, 32), dim3(256), 0, stream>>>(
            m1, wfc2T, b_fc2, x2, out, 4096, 1024, 4096, 0, 1);
    } else {
        float*          x2  = (float*)(ws + ((size_t)24u << 20));
        unsigned short* m1c = (unsigned short*)(ws + ((size_t)40u << 20));
        unsigned short* h2  = (unsigned short*)d_out + ((size_t)4u << 20);
        attn_kernel<<<dim3(32, 32), dim3(256), 0, stream>>>(qkv, sb);
        gemm_kernel<64><<<dim3(16, 32), dim3(256), 0, stream>>>(
            sb, wprojT, b_proj, x, x2, 4096, 1024, 1024, 0, 1);
        ln_kernel<<<dim3(4096), dim3(256), 0, stream>>>(x2, g2, be2, h2);
        for (int c = 0; c < 4; ++c) {
            size_t ro = (size_t)c * 1024;
            gemm_kernel<128><<<dim3(32, 8), dim3(256), 0, stream>>>(
                h2 + ro * 1024, wfc1T, b_fc1, nullptr, m1c, 1024, 4096, 1024, 1, 0);
            gemm_kernel<64><<<dim3(16, 8), dim3(256), 0, stream>>>(
                m1c, wfc2T, b_fc2, x2 + ro * 1024, out + ro * 1024, 1024, 1024, 4096, 0, 1);
        }
    }
}